// Round 2
// baseline (352.687 us; speedup 1.0000x reference)
//
#include <hip/hip_runtime.h>
#include <hip/hip_bf16.h>

#define G     32
#define NPG   512
#define EPG   8192
#define GN    16384        // G*NPG
#define ETOT  (G*EPG)      // 262144
#define CIN   64
#define H     128
#define NB    4
#define S     4096         // T*NPG
#define HEADS 4
#define HD    32
#define QKV   384

typedef __attribute__((ext_vector_type(8))) short short8;
typedef __attribute__((ext_vector_type(4))) float floatx4;

__device__ __forceinline__ float bf16_to_f32(unsigned short u) {
    unsigned int x = ((unsigned int)u) << 16;
    return __uint_as_float(x);
}
__device__ __forceinline__ unsigned short f32_to_bf16(float f) {
    __hip_bfloat16 h = (__hip_bfloat16)f;
    return *(unsigned short*)&h;
}
__device__ __forceinline__ float ldf(const void* p, long i, int f32) {
    return f32 ? ((const float*)p)[i] : bf16_to_f32(((const unsigned short*)p)[i]);
}

// ---------- runtime dtype detection ----------
__global__ void detect_kernel(const unsigned short* __restrict__ xraw,
                              const int* __restrict__ eiraw, int* __restrict__ flags) {
    __shared__ float smax[256];
    __shared__ int   sor[256];
    int t = threadIdx.x;
    float m = 0.f;
    for (int i = t; i < 4096; i += 256)
        m = fmaxf(m, fabsf(bf16_to_f32(xraw[i])));
    int orv = 0;
    for (int i = t; i < 2048; i += 256)
        orv |= eiraw[2 * i + 1];
    smax[t] = m; sor[t] = orv;
    __syncthreads();
    for (int off = 128; off > 0; off >>= 1) {
        if (t < off) {
            smax[t] = fmaxf(smax[t], smax[t + off]);
            sor[t] |= sor[t + off];
        }
        __syncthreads();
    }
    if (t == 0) {
        flags[0] = (smax[0] > 1000.f) ? 1 : 0;
        flags[1] = (sor[0] == 0) ? 1 : 0;
    }
}

// ---------- fused conversion: everything -> bf16 (weights pre-transposed) ----------
#define XN   (GN*CIN)          // x:      [0,      XN)
#define E1   (XN + H*CIN)      // W1T
#define E2   (E1 + H*H)        // W2T
#define E3   (E2 + QKV*H)      // Wqkv
#define E4   (E3 + H*H)        // Wo
#define E5   (E4 + H)          // b1
#define E6   (E5 + H)          // b2
#define E7   (E6 + QKV)        // bqkv
#define CTOT (E7 + H)          // bo
__global__ void conv_all_kernel(const void* x_raw, const void* W1_raw, const void* b1_raw,
                                const void* W2_raw, const void* b2_raw, const void* Wq_raw,
                                const void* bq_raw, const void* Wo_raw, const void* bo_raw,
                                unsigned short* __restrict__ xb,
                                unsigned short* __restrict__ W1T,
                                unsigned short* __restrict__ W2T,
                                unsigned short* __restrict__ Wqb,
                                unsigned short* __restrict__ Wob,
                                float* __restrict__ b1f, float* __restrict__ b2f,
                                float* __restrict__ bqf, float* __restrict__ bof,
                                const int* __restrict__ flags) {
    int i = blockIdx.x * blockDim.x + threadIdx.x;
    if (i >= CTOT) return;
    int f32 = flags[0];
    if (i < XN) {
        xb[i] = f32_to_bf16(ldf(x_raw, i, f32));
    } else if (i < E1) {       // W1T[c][r] = W1[r][c], [H out][CIN in]
        int j = i - XN, c = j / CIN, r = j - c * CIN;
        W1T[j] = f32_to_bf16(ldf(W1_raw, (long)r * H + c, f32));
    } else if (i < E2) {       // W2T[c][r] = W2[r][c]
        int j = i - E1, c = j >> 7, r = j & 127;
        W2T[j] = f32_to_bf16(ldf(W2_raw, (long)r * H + c, f32));
    } else if (i < E3) {       // in_proj_w already [out][in]
        int j = i - E2;
        Wqb[j] = f32_to_bf16(ldf(Wq_raw, j, f32));
    } else if (i < E4) {
        int j = i - E3;
        Wob[j] = f32_to_bf16(ldf(Wo_raw, j, f32));
    } else if (i < E5) { b1f[i - E4] = ldf(b1_raw, i - E4, f32); }
    else if (i < E6) { b2f[i - E5] = ldf(b2_raw, i - E5, f32); }
    else if (i < E7) { bqf[i - E6] = ldf(bq_raw, i - E6, f32); }
    else             { bof[i - E7] = ldf(bo_raw, i - E7, f32); }
}

// ---------- edges / CSR ----------
__global__ void edges_kernel(const int* __restrict__ ei, int* __restrict__ srcA,
                             int* __restrict__ dstA, const int* __restrict__ flags) {
    int t = blockIdx.x * blockDim.x + threadIdx.x;
    if (t >= ETOT) return;
    int g = t >> 13, e = t & (EPG - 1);
    int sh = flags[1];
    long long si = ((long long)(g * 2 + 0) * EPG + e) << sh;
    long long di = ((long long)(g * 2 + 1) * EPG + e) << sh;
    srcA[t] = g * NPG + ei[si];
    dstA[t] = g * NPG + ei[di];
}

__global__ void count_kernel(const int* __restrict__ dstA, int* __restrict__ cnt) {
    int t = blockIdx.x * blockDim.x + threadIdx.x;
    if (t >= ETOT) return;
    atomicAdd(&cnt[dstA[t]], 1);
}

__global__ void scan_kernel(const int* __restrict__ cnt, int* __restrict__ row_start,
                            int* __restrict__ fill_pos, float* __restrict__ dinv) {
    __shared__ int tmp[NPG];
    int g = blockIdx.x, t = threadIdx.x;
    int c = cnt[g * NPG + t];
    tmp[t] = c;
    __syncthreads();
    for (int off = 1; off < NPG; off <<= 1) {
        int v = (t >= off) ? tmp[t - off] : 0;
        __syncthreads();
        tmp[t] += v;
        __syncthreads();
    }
    int excl = tmp[t] - c;
    int rs = g * EPG + excl;
    row_start[g * NPG + t] = rs;
    fill_pos[g * NPG + t]  = rs;
    dinv[g * NPG + t] = 1.0f / sqrtf((float)c + 1.0f);
}

__global__ void fill_kernel(const int* __restrict__ srcA, const int* __restrict__ dstA,
                            int* __restrict__ fill_pos, int* __restrict__ csr_src) {
    int t = blockIdx.x * blockDim.x + threadIdx.x;
    if (t >= ETOT) return;
    int pos = atomicAdd(&fill_pos[dstA[t]], 1);
    csr_src[pos] = srcA[t];
}

// ---------- MFMA GEMM: Y[row][col] = (A[row][:] . B[col][:]) * dinv[row]  (bf16 out)
template<int KD>
__global__ __launch_bounds__(256) void mm_gcn_kernel(const unsigned short* __restrict__ A,
        const unsigned short* __restrict__ B, const float* __restrict__ dinv,
        unsigned short* __restrict__ Y) {
    int tid = threadIdx.x, wave = tid >> 6, lane = tid & 63, m = lane & 15, quad = lane >> 4;
    int row0 = blockIdx.x * 64 + wave * 16;
    floatx4 acc[8] = {};
    for (int kc = 0; kc < KD; kc += 32) {
        short8 af = *(const short8*)&A[(size_t)(row0 + m) * KD + kc + quad * 8];
#pragma unroll
        for (int t = 0; t < 8; t++) {
            short8 bf = *(const short8*)&B[(size_t)(t * 16 + m) * KD + kc + quad * 8];
            acc[t] = __builtin_amdgcn_mfma_f32_16x16x32_bf16(af, bf, acc[t], 0, 0, 0);
        }
    }
    int rbase = row0 + quad * 4;
    float4 dv4 = *(const float4*)&dinv[rbase];
    float dv[4] = {dv4.x, dv4.y, dv4.z, dv4.w};
#pragma unroll
    for (int t = 0; t < 8; t++) {
        int col = t * 16 + m;
#pragma unroll
        for (int r = 0; r < 4; r++)
            Y[(size_t)(rbase + r) * H + col] = f32_to_bf16(acc[t][r] * dv[r]);
    }
}

// ---------- GCN aggregation (bf16 in/out, f32 accum), gather unrolled x4 ----------
__global__ void agg_kernel(const unsigned short* __restrict__ y,
                           const int* __restrict__ row_start, const int* __restrict__ cnt,
                           const int* __restrict__ csr_src, const float* __restrict__ dinv,
                           const float* __restrict__ bias, unsigned short* __restrict__ hout) {
    int i = blockIdx.x;
    int c = threadIdx.x;
    float acc = bf16_to_f32(y[(size_t)i * H + c]);   // self-loop
    int rs = row_start[i], n = cnt[i];
    int p = 0;
    for (; p + 4 <= n; p += 4) {
        int s0 = csr_src[rs + p + 0];
        int s1 = csr_src[rs + p + 1];
        int s2 = csr_src[rs + p + 2];
        int s3 = csr_src[rs + p + 3];
        float a0 = bf16_to_f32(y[(size_t)s0 * H + c]);
        float a1 = bf16_to_f32(y[(size_t)s1 * H + c]);
        float a2 = bf16_to_f32(y[(size_t)s2 * H + c]);
        float a3 = bf16_to_f32(y[(size_t)s3 * H + c]);
        acc += (a0 + a1) + (a2 + a3);
    }
    for (; p < n; p++)
        acc += bf16_to_f32(y[(size_t)csr_src[rs + p] * H + c]);
    hout[(size_t)i * H + c] = f32_to_bf16(acc * dinv[i] + bias[c]);
}

// ---------- QKV GEMM (N=384) with blocked epilogue ----------
// Q pre-scale folds log2(e) so attention can use raw v_exp_f32 (2^x).
__global__ __launch_bounds__(256) void mmqkv_kernel(const unsigned short* __restrict__ A,
        const unsigned short* __restrict__ B, const float* __restrict__ bias,
        unsigned short* __restrict__ Qx, unsigned short* __restrict__ Kx,
        unsigned short* __restrict__ Vtx) {
    int tid = threadIdx.x, wave = tid >> 6, lane = tid & 63, m = lane & 15, quad = lane >> 4;
    int row0 = blockIdx.x * 64 + wave * 16;
    floatx4 acc[24] = {};
    for (int kc = 0; kc < H; kc += 32) {
        short8 af = *(const short8*)&A[(size_t)(row0 + m) * H + kc + quad * 8];
#pragma unroll
        for (int t = 0; t < 24; t++) {
            short8 bf = *(const short8*)&B[(size_t)(t * 16 + m) * H + kc + quad * 8];
            acc[t] = __builtin_amdgcn_mfma_f32_16x16x32_bf16(af, bf, acc[t], 0, 0, 0);
        }
    }
    int rbase = row0 + quad * 4;                    // rows rbase..rbase+3, same batch
    int b = rbase >> 12, s0 = rbase & (S - 1);
#pragma unroll
    for (int t = 0; t < 24; t++) {
        int j = t * 16 + m;                         // 0..383
        float bj = bias[j];
        int jj = j & 127, head = jj >> 5, hd = jj & 31;
        int bh = b * HEADS + head;
        if (t < 8) {                                // Q (pre-scaled by log2e/sqrt(hd))
#pragma unroll
            for (int r = 0; r < 4; r++)
                Qx[((size_t)bh * S + s0 + r) * HD + hd] =
                    f32_to_bf16((acc[t][r] + bj) *
                                (0.17677669529663687f * 1.4426950408889634f));
        } else if (t < 16) {                        // K
#pragma unroll
            for (int r = 0; r < 4; r++)
                Kx[((size_t)bh * S + s0 + r) * HD + hd] = f32_to_bf16(acc[t][r] + bj);
        } else {                                    // V transposed
#pragma unroll
            for (int r = 0; r < 4; r++)
                Vtx[((size_t)bh * HD + hd) * S + s0 + r] = f32_to_bf16(acc[t][r] + bj);
        }
    }
}

// ---------- MFMA flash attention v5: zero-LDS, in-register P transpose,
// 16 q-rows/wave for 2x occupancy (grid-limited before: 2 waves/SIMD -> 4).
// Swapped QK^T (mfma(K,Q)) puts a full P row per lane; cvt_pk_bf16 packs pairs and
// permlane32/16_swap redistribute them into the exact PV A-fragment layout
// (lane(m,quad) = P[q=m][k=8*quad..8*quad+7]).  Softmax denominator l is computed
// on the MFMA pipe (P x ones fragment) and lands row-aligned with the O accumulators.
// The 4 waves of a block read identical K/V addresses -> L1 dedups the traffic.
// grid (S/64, HEADS, NB), block 256, LDS 0.
__global__ __launch_bounds__(256) void attn5_kernel(
        const unsigned short* __restrict__ Qx, const unsigned short* __restrict__ Kx,
        const unsigned short* __restrict__ Vtx, unsigned short* __restrict__ Ob) {
    int tid = threadIdx.x, wave = tid >> 6, lane = tid & 63;
    int m = lane & 15, quad = lane >> 4;
    int bh = blockIdx.z * HEADS + blockIdx.y;
    const unsigned short* Qb  = Qx  + (size_t)bh * S * HD;
    const unsigned short* Kb  = Kx  + (size_t)bh * S * HD;
    const unsigned short* Vtb = Vtx + (size_t)bh * HD * S;

    int q0 = blockIdx.x * 64 + wave * 16;
    short8 qa = *(const short8*)&Qb[(size_t)(q0 + m) * HD + quad * 8];

    floatx4 oa0 = {}, oa1 = {};
    floatx4 la = {};                                // row-sum accumulator (MFMA pipe)

    short8 ones = {16256, 16256, 16256, 16256, 16256, 16256, 16256, 16256}; // bf16 1.0

    // chunk 0 K/V
    short8 kf0 = *(const short8*)&Kb[(size_t)m * HD + quad * 8];
    short8 kf1 = *(const short8*)&Kb[(size_t)(m + 16) * HD + quad * 8];
    short8 vc0 = *(const short8*)&Vtb[(size_t)m * S + quad * 8];
    short8 vc1 = *(const short8*)&Vtb[(size_t)(m + 16) * S + quad * 8];

    for (int i = 0; i < S / 32; i++) {
        // swapped QK^T: lane(m,quad) gets P^T[k=quad*4+r][q=m] (kf1: k+16)
        floatx4 z = {};
        floatx4 ta0 = __builtin_amdgcn_mfma_f32_16x16x32_bf16(kf0, qa, z, 0, 0, 0);
        floatx4 ta1 = __builtin_amdgcn_mfma_f32_16x16x32_bf16(kf1, qa, z, 0, 0, 0);

        // rotate V, prefetch chunk i+1 (wrap: harmless valid loads)
        short8 vp0 = vc0, vp1 = vc1;
        int ktn = ((i + 1) * 32) & (S - 1);
        kf0 = *(const short8*)&Kb[(size_t)(ktn + m) * HD + quad * 8];
        kf1 = *(const short8*)&Kb[(size_t)(ktn + m + 16) * HD + quad * 8];
        vc0 = *(const short8*)&Vtb[(size_t)m * S + ktn + quad * 8];
        vc1 = *(const short8*)&Vtb[(size_t)(m + 16) * S + ktn + quad * 8];

        // exp2 (Q was pre-scaled by log2e/sqrt(hd)) -> raw v_exp_f32, no mul
        float pa0 = __builtin_amdgcn_exp2f(ta0[0]);
        float pa1 = __builtin_amdgcn_exp2f(ta0[1]);
        float pa2 = __builtin_amdgcn_exp2f(ta0[2]);
        float pa3 = __builtin_amdgcn_exp2f(ta0[3]);
        float pa4 = __builtin_amdgcn_exp2f(ta1[0]);
        float pa5 = __builtin_amdgcn_exp2f(ta1[1]);
        float pa6 = __builtin_amdgcn_exp2f(ta1[2]);
        float pa7 = __builtin_amdgcn_exp2f(ta1[3]);

        // pack pairs to bf16 (one op per 2 converts)
        unsigned int wa0, wa1, wa2, wa3;
        asm("v_cvt_pk_bf16_f32 %0, %1, %2" : "=v"(wa0) : "v"(pa0), "v"(pa1));
        asm("v_cvt_pk_bf16_f32 %0, %1, %2" : "=v"(wa1) : "v"(pa2), "v"(pa3));
        asm("v_cvt_pk_bf16_f32 %0, %1, %2" : "=v"(wa2) : "v"(pa4), "v"(pa5));
        asm("v_cvt_pk_bf16_f32 %0, %1, %2" : "=v"(wa3) : "v"(pa6), "v"(pa7));

        // in-register transpose: hi-half(dst) <-> lo-half(src), then row1<->row0 per pair
        asm("v_permlane32_swap_b32 %0, %1" : "+v"(wa0), "+v"(wa2));
        asm("v_permlane32_swap_b32 %0, %1" : "+v"(wa1), "+v"(wa3));
        asm("v_permlane16_swap_b32 %0, %1" : "+v"(wa0), "+v"(wa2));
        asm("v_permlane16_swap_b32 %0, %1" : "+v"(wa1), "+v"(wa3));

        union PW { unsigned int u[4]; short8 s8; };
        PW pwa;
        pwa.u[0] = wa0; pwa.u[1] = wa1; pwa.u[2] = wa2; pwa.u[3] = wa3;

        // PV + row-sum l, all on the MFMA pipe
        oa0 = __builtin_amdgcn_mfma_f32_16x16x32_bf16(pwa.s8, vp0, oa0, 0, 0, 0);
        oa1 = __builtin_amdgcn_mfma_f32_16x16x32_bf16(pwa.s8, vp1, oa1, 0, 0, 0);
        la  = __builtin_amdgcn_mfma_f32_16x16x32_bf16(pwa.s8, ones, la, 0, 0, 0);
    }

    // epilogue: l is already row-aligned with O (row = quad*4+r), no shuffles
    int grow = blockIdx.z * S + q0 + quad * 4;
    int col = blockIdx.y * HD + m;
#pragma unroll
    for (int r = 0; r < 4; r++) {
        float iar = 1.f / la[r];
        Ob[(size_t)(grow + r) * H + col]      = f32_to_bf16(oa0[r] * iar);
        Ob[(size_t)(grow + r) * H + col + 16] = f32_to_bf16(oa1[r] * iar);
    }
}

// ---------- output projection GEMM (N=128) + bias, dual-dtype store ----------
__global__ __launch_bounds__(256) void mmout_kernel(const unsigned short* __restrict__ A,
        const unsigned short* __restrict__ B, const float* __restrict__ bias,
        void* __restrict__ out, const int* __restrict__ flags) {
    int tid = threadIdx.x, wave = tid >> 6, lane = tid & 63, m = lane & 15, quad = lane >> 4;
    int row0 = blockIdx.x * 64 + wave * 16;
    floatx4 acc[8] = {};
    for (int kc = 0; kc < H; kc += 32) {
        short8 af = *(const short8*)&A[(size_t)(row0 + m) * H + kc + quad * 8];
#pragma unroll
        for (int t = 0; t < 8; t++) {
            short8 bf = *(const short8*)&B[(size_t)(t * 16 + m) * H + kc + quad * 8];
            acc[t] = __builtin_amdgcn_mfma_f32_16x16x32_bf16(af, bf, acc[t], 0, 0, 0);
        }
    }
    int rbase = row0 + quad * 4;
    int f32o = flags[0];
#pragma unroll
    for (int t = 0; t < 8; t++) {
        int col = t * 16 + m;
        float bj = bias[col];
#pragma unroll
        for (int r = 0; r < 4; r++) {
            float v = acc[t][r] + bj;
            if (f32o) ((float*)out)[(size_t)(rbase + r) * H + col] = v;
            else ((unsigned short*)out)[(size_t)(rbase + r) * H + col] = f32_to_bf16(v);
        }
    }
}

extern "C" void kernel_launch(void* const* d_in, const int* in_sizes, int n_in,
                              void* d_out, int out_size, void* d_ws, size_t ws_size,
                              hipStream_t stream) {
    const void* x_raw    = d_in[0];
    const int*  ei_raw   = (const int*)d_in[1];
    const void* W1_raw   = d_in[2];
    const void* b1_raw   = d_in[3];
    const void* W2_raw   = d_in[4];
    const void* b2_raw   = d_in[5];
    const void* Wq_raw   = d_in[6];
    const void* bq_raw   = d_in[7];
    const void* Wo_raw   = d_in[8];
    const void* bo_raw   = d_in[9];

    char* ws = (char*)d_ws;
    size_t o = 0;
    auto alloc = [&](size_t bytes) { void* p = ws + o; o += (bytes + 1023) & ~1023ull; return p; };

    int*   flags     = (int*)  alloc(1024);
    int*   cnt       = (int*)  alloc((size_t)GN * 4);
    int*   row_start = (int*)  alloc((size_t)GN * 4);
    int*   fill_pos  = (int*)  alloc((size_t)GN * 4);
    float* dinv      = (float*)alloc((size_t)GN * 4);
    int*   srcA      = (int*)  alloc((size_t)ETOT * 4);
    int*   dstA      = (int*)  alloc((size_t)ETOT * 4);
    int*   csr_src   = (int*)  alloc((size_t)ETOT * 4);
    unsigned short* xb   = (unsigned short*)alloc((size_t)GN * CIN * 2);
    unsigned short* W1T  = (unsigned short*)alloc((size_t)H * CIN * 2);
    unsigned short* W2T  = (unsigned short*)alloc((size_t)H * H * 2);
    unsigned short* Wqb  = (unsigned short*)alloc((size_t)QKV * H * 2);
    unsigned short* Wob  = (unsigned short*)alloc((size_t)H * H * 2);
    float* b1f = (float*)alloc(H * 4);
    float* b2f = (float*)alloc(H * 4);
    float* bqf = (float*)alloc(QKV * 4);
    float* bof = (float*)alloc(H * 4);
    unsigned short* y_bf = (unsigned short*)alloc((size_t)GN * H * 2);
    unsigned short* h_bf = (unsigned short*)alloc((size_t)GN * H * 2);
    unsigned short* Qx   = (unsigned short*)alloc((size_t)16 * S * HD * 2);
    unsigned short* Kx   = (unsigned short*)alloc((size_t)16 * S * HD * 2);
    unsigned short* Vtx  = (unsigned short*)alloc((size_t)16 * S * HD * 2);
    unsigned short* Obf  = y_bf;   // y dead after second agg

    detect_kernel<<<1, 256, 0, stream>>>((const unsigned short*)x_raw, ei_raw, flags);

    conv_all_kernel<<<(CTOT + 255) / 256, 256, 0, stream>>>(
        x_raw, W1_raw, b1_raw, W2_raw, b2_raw, Wq_raw, bq_raw, Wo_raw, bo_raw,
        xb, W1T, W2T, Wqb, Wob, b1f, b2f, bqf, bof, flags);

    edges_kernel<<<ETOT / 256, 256, 0, stream>>>(ei_raw, srcA, dstA, flags);
    hipMemsetAsync(cnt, 0, (size_t)GN * 4, stream);
    count_kernel<<<ETOT / 256, 256, 0, stream>>>(dstA, cnt);
    scan_kernel<<<G, NPG, 0, stream>>>(cnt, row_start, fill_pos, dinv);
    fill_kernel<<<ETOT / 256, 256, 0, stream>>>(srcA, dstA, fill_pos, csr_src);

    // GCN layer 1
    mm_gcn_kernel<CIN><<<GN / 64, 256, 0, stream>>>(xb, W1T, dinv, y_bf);
    agg_kernel<<<GN, H, 0, stream>>>(y_bf, row_start, cnt, csr_src, dinv, b1f, h_bf);
    // GCN layer 2
    mm_gcn_kernel<H><<<GN / 64, 256, 0, stream>>>(h_bf, W2T, dinv, y_bf);
    agg_kernel<<<GN, H, 0, stream>>>(y_bf, row_start, cnt, csr_src, dinv, b2f, h_bf);

    // attention
    mmqkv_kernel<<<GN / 64, 256, 0, stream>>>(h_bf, Wqb, bqf, Qx, Kx, Vtx);
    attn5_kernel<<<dim3(S / 64, HEADS, NB), 256, 0, stream>>>(Qx, Kx, Vtx, Obf);
    mmout_kernel<<<GN / 64, 256, 0, stream>>>(Obf, Wob, bof, d_out, flags);
}

// Round 3
// 274.494 us; speedup vs baseline: 1.2849x; 1.2849x over previous
//
#include <hip/hip_runtime.h>
#include <hip/hip_bf16.h>

#define G     32
#define NPG   512
#define EPG   8192
#define GN    16384        // G*NPG
#define ETOT  (G*EPG)      // 262144
#define CIN   64
#define H     128
#define NB    4
#define S     4096         // T*NPG
#define HEADS 4
#define HD    32
#define QKV   384

typedef __attribute__((ext_vector_type(8))) short short8;
typedef __attribute__((ext_vector_type(4))) float floatx4;

__device__ __forceinline__ float bf16_to_f32(unsigned short u) {
    unsigned int x = ((unsigned int)u) << 16;
    return __uint_as_float(x);
}
__device__ __forceinline__ unsigned short f32_to_bf16(float f) {
    __hip_bfloat16 h = (__hip_bfloat16)f;
    return *(unsigned short*)&h;
}
__device__ __forceinline__ float ldf(const void* p, long i, int f32) {
    return f32 ? ((const float*)p)[i] : bf16_to_f32(((const unsigned short*)p)[i]);
}

// ---------- runtime dtype detection ----------
__global__ void detect_kernel(const unsigned short* __restrict__ xraw,
                              const int* __restrict__ eiraw, int* __restrict__ flags) {
    __shared__ float smax[256];
    __shared__ int   sor[256];
    int t = threadIdx.x;
    float m = 0.f;
    for (int i = t; i < 4096; i += 256)
        m = fmaxf(m, fabsf(bf16_to_f32(xraw[i])));
    int orv = 0;
    for (int i = t; i < 2048; i += 256)
        orv |= eiraw[2 * i + 1];
    smax[t] = m; sor[t] = orv;
    __syncthreads();
    for (int off = 128; off > 0; off >>= 1) {
        if (t < off) {
            smax[t] = fmaxf(smax[t], smax[t + off]);
            sor[t] |= sor[t + off];
        }
        __syncthreads();
    }
    if (t == 0) {
        flags[0] = (smax[0] > 1000.f) ? 1 : 0;
        flags[1] = (sor[0] == 0) ? 1 : 0;
    }
}

// ---------- fused conversion: everything -> bf16 (weights pre-transposed) ----------
#define XN   (GN*CIN)          // x:      [0,      XN)
#define E1   (XN + H*CIN)      // W1T
#define E2   (E1 + H*H)        // W2T
#define E3   (E2 + QKV*H)      // Wqkv
#define E4   (E3 + H*H)        // Wo
#define E5   (E4 + H)          // b1
#define E6   (E5 + H)          // b2
#define E7   (E6 + QKV)        // bqkv
#define CTOT (E7 + H)          // bo
__global__ void conv_all_kernel(const void* x_raw, const void* W1_raw, const void* b1_raw,
                                const void* W2_raw, const void* b2_raw, const void* Wq_raw,
                                const void* bq_raw, const void* Wo_raw, const void* bo_raw,
                                unsigned short* __restrict__ xb,
                                unsigned short* __restrict__ W1T,
                                unsigned short* __restrict__ W2T,
                                unsigned short* __restrict__ Wqb,
                                unsigned short* __restrict__ Wob,
                                float* __restrict__ b1f, float* __restrict__ b2f,
                                float* __restrict__ bqf, float* __restrict__ bof,
                                const int* __restrict__ flags) {
    int i = blockIdx.x * blockDim.x + threadIdx.x;
    if (i >= CTOT) return;
    int f32 = flags[0];
    if (i < XN) {
        xb[i] = f32_to_bf16(ldf(x_raw, i, f32));
    } else if (i < E1) {       // W1T[c][r] = W1[r][c], [H out][CIN in]
        int j = i - XN, c = j / CIN, r = j - c * CIN;
        W1T[j] = f32_to_bf16(ldf(W1_raw, (long)r * H + c, f32));
    } else if (i < E2) {       // W2T[c][r] = W2[r][c]
        int j = i - E1, c = j >> 7, r = j & 127;
        W2T[j] = f32_to_bf16(ldf(W2_raw, (long)r * H + c, f32));
    } else if (i < E3) {       // in_proj_w already [out][in]
        int j = i - E2;
        Wqb[j] = f32_to_bf16(ldf(Wq_raw, j, f32));
    } else if (i < E4) {
        int j = i - E3;
        Wob[j] = f32_to_bf16(ldf(Wo_raw, j, f32));
    } else if (i < E5) { b1f[i - E4] = ldf(b1_raw, i - E4, f32); }
    else if (i < E6) { b2f[i - E5] = ldf(b2_raw, i - E5, f32); }
    else if (i < E7) { bqf[i - E6] = ldf(bq_raw, i - E6, f32); }
    else             { bof[i - E7] = ldf(bo_raw, i - E7, f32); }
}

// ---------- edges / CSR ----------
__global__ void edges_kernel(const int* __restrict__ ei, int* __restrict__ srcA,
                             int* __restrict__ dstA, const int* __restrict__ flags) {
    int t = blockIdx.x * blockDim.x + threadIdx.x;
    if (t >= ETOT) return;
    int g = t >> 13, e = t & (EPG - 1);
    int sh = flags[1];
    long long si = ((long long)(g * 2 + 0) * EPG + e) << sh;
    long long di = ((long long)(g * 2 + 1) * EPG + e) << sh;
    srcA[t] = g * NPG + ei[si];
    dstA[t] = g * NPG + ei[di];
}

__global__ void count_kernel(const int* __restrict__ dstA, int* __restrict__ cnt) {
    int t = blockIdx.x * blockDim.x + threadIdx.x;
    if (t >= ETOT) return;
    atomicAdd(&cnt[dstA[t]], 1);
}

__global__ void scan_kernel(const int* __restrict__ cnt, int* __restrict__ row_start,
                            int* __restrict__ fill_pos, float* __restrict__ dinv) {
    __shared__ int tmp[NPG];
    int g = blockIdx.x, t = threadIdx.x;
    int c = cnt[g * NPG + t];
    tmp[t] = c;
    __syncthreads();
    for (int off = 1; off < NPG; off <<= 1) {
        int v = (t >= off) ? tmp[t - off] : 0;
        __syncthreads();
        tmp[t] += v;
        __syncthreads();
    }
    int excl = tmp[t] - c;
    int rs = g * EPG + excl;
    row_start[g * NPG + t] = rs;
    fill_pos[g * NPG + t]  = rs;
    dinv[g * NPG + t] = 1.0f / sqrtf((float)c + 1.0f);
}

__global__ void fill_kernel(const int* __restrict__ srcA, const int* __restrict__ dstA,
                            int* __restrict__ fill_pos, int* __restrict__ csr_src) {
    int t = blockIdx.x * blockDim.x + threadIdx.x;
    if (t >= ETOT) return;
    int pos = atomicAdd(&fill_pos[dstA[t]], 1);
    csr_src[pos] = srcA[t];
}

// ---------- MFMA GEMM: Y[row][col] = (A[row][:] . B[col][:]) * dinv[row]  (bf16 out)
template<int KD>
__global__ __launch_bounds__(256) void mm_gcn_kernel(const unsigned short* __restrict__ A,
        const unsigned short* __restrict__ B, const float* __restrict__ dinv,
        unsigned short* __restrict__ Y) {
    int tid = threadIdx.x, wave = tid >> 6, lane = tid & 63, m = lane & 15, quad = lane >> 4;
    int row0 = blockIdx.x * 64 + wave * 16;
    floatx4 acc[8] = {};
    for (int kc = 0; kc < KD; kc += 32) {
        short8 af = *(const short8*)&A[(size_t)(row0 + m) * KD + kc + quad * 8];
#pragma unroll
        for (int t = 0; t < 8; t++) {
            short8 bf = *(const short8*)&B[(size_t)(t * 16 + m) * KD + kc + quad * 8];
            acc[t] = __builtin_amdgcn_mfma_f32_16x16x32_bf16(af, bf, acc[t], 0, 0, 0);
        }
    }
    int rbase = row0 + quad * 4;
    float4 dv4 = *(const float4*)&dinv[rbase];
    float dv[4] = {dv4.x, dv4.y, dv4.z, dv4.w};
#pragma unroll
    for (int t = 0; t < 8; t++) {
        int col = t * 16 + m;
#pragma unroll
        for (int r = 0; r < 4; r++)
            Y[(size_t)(rbase + r) * H + col] = f32_to_bf16(acc[t][r] * dv[r]);
    }
}

// ---------- GCN aggregation (bf16 in/out, f32 accum), gather unrolled x4 ----------
__global__ void agg_kernel(const unsigned short* __restrict__ y,
                           const int* __restrict__ row_start, const int* __restrict__ cnt,
                           const int* __restrict__ csr_src, const float* __restrict__ dinv,
                           const float* __restrict__ bias, unsigned short* __restrict__ hout) {
    int i = blockIdx.x;
    int c = threadIdx.x;
    float acc = bf16_to_f32(y[(size_t)i * H + c]);   // self-loop
    int rs = row_start[i], n = cnt[i];
    int p = 0;
    for (; p + 4 <= n; p += 4) {
        int s0 = csr_src[rs + p + 0];
        int s1 = csr_src[rs + p + 1];
        int s2 = csr_src[rs + p + 2];
        int s3 = csr_src[rs + p + 3];
        float a0 = bf16_to_f32(y[(size_t)s0 * H + c]);
        float a1 = bf16_to_f32(y[(size_t)s1 * H + c]);
        float a2 = bf16_to_f32(y[(size_t)s2 * H + c]);
        float a3 = bf16_to_f32(y[(size_t)s3 * H + c]);
        acc += (a0 + a1) + (a2 + a3);
    }
    for (; p < n; p++)
        acc += bf16_to_f32(y[(size_t)csr_src[rs + p] * H + c]);
    hout[(size_t)i * H + c] = f32_to_bf16(acc * dinv[i] + bias[c]);
}

// ---------- QKV GEMM (N=384) with blocked epilogue ----------
// Q pre-scale folds log2(e) so attention can use raw v_exp_f32 (2^x).
__global__ __launch_bounds__(256) void mmqkv_kernel(const unsigned short* __restrict__ A,
        const unsigned short* __restrict__ B, const float* __restrict__ bias,
        unsigned short* __restrict__ Qx, unsigned short* __restrict__ Kx,
        unsigned short* __restrict__ Vtx) {
    int tid = threadIdx.x, wave = tid >> 6, lane = tid & 63, m = lane & 15, quad = lane >> 4;
    int row0 = blockIdx.x * 64 + wave * 16;
    floatx4 acc[24] = {};
    for (int kc = 0; kc < H; kc += 32) {
        short8 af = *(const short8*)&A[(size_t)(row0 + m) * H + kc + quad * 8];
#pragma unroll
        for (int t = 0; t < 24; t++) {
            short8 bf = *(const short8*)&B[(size_t)(t * 16 + m) * H + kc + quad * 8];
            acc[t] = __builtin_amdgcn_mfma_f32_16x16x32_bf16(af, bf, acc[t], 0, 0, 0);
        }
    }
    int rbase = row0 + quad * 4;                    // rows rbase..rbase+3, same batch
    int b = rbase >> 12, s0 = rbase & (S - 1);
#pragma unroll
    for (int t = 0; t < 24; t++) {
        int j = t * 16 + m;                         // 0..383
        float bj = bias[j];
        int jj = j & 127, head = jj >> 5, hd = jj & 31;
        int bh = b * HEADS + head;
        if (t < 8) {                                // Q (pre-scaled by log2e/sqrt(hd))
#pragma unroll
            for (int r = 0; r < 4; r++)
                Qx[((size_t)bh * S + s0 + r) * HD + hd] =
                    f32_to_bf16((acc[t][r] + bj) *
                                (0.17677669529663687f * 1.4426950408889634f));
        } else if (t < 16) {                        // K
#pragma unroll
            for (int r = 0; r < 4; r++)
                Kx[((size_t)bh * S + s0 + r) * HD + hd] = f32_to_bf16(acc[t][r] + bj);
        } else {                                    // V transposed
#pragma unroll
            for (int r = 0; r < 4; r++)
                Vtx[((size_t)bh * HD + hd) * S + s0 + r] = f32_to_bf16(acc[t][r] + bj);
        }
    }
}

// ---------- MFMA flash attention v6 ----------
// attn4 structure (32 q-rows/wave, zero-LDS, in-register P transpose) plus:
//  (1) XCD swizzle: 1-D grid 512; id=(n&7)*64+(n>>3) gives each XCD 2 bh-streams
//      (1 MB K+V << 4 MB XCD-L2) -> K/V loads become L2 hits, no HBM re-fetch.
//  (2) 2-chunk software pipeline: chunks i and i+1 carried in independent register
//      sets; K prefetched 2 chunks ahead right after QK frees the old fragment,
//      V right after PV. ~2 chunk bodies of issue between load and use covers
//      L2-hit latency; B-chain exp/pack VALU overlaps A-chain PV MFMAs.
// grid 512, block 256 (4 waves), LDS 0.
__global__ __launch_bounds__(256, 2) void attn6_kernel(
        const unsigned short* __restrict__ Qx, const unsigned short* __restrict__ Kx,
        const unsigned short* __restrict__ Vtx, unsigned short* __restrict__ Ob) {
    int tid = threadIdx.x, wave = tid >> 6, lane = tid & 63;
    int m = lane & 15, quad = lane >> 4;

    int n = blockIdx.x;                       // 0..511, XCD ~ n%8
    int id = (n & 7) * 64 + (n >> 3);         // XCD x owns ids [64x, 64x+64) -> bh {2x,2x+1}
    int tile = id & 31, bh = id >> 5;

    const unsigned short* Qb  = Qx  + (size_t)bh * S * HD;
    const unsigned short* Kb  = Kx  + (size_t)bh * S * HD;
    const unsigned short* Vtb = Vtx + (size_t)bh * HD * S;

    int q0 = tile * 128 + wave * 32;
    short8 qa = *(const short8*)&Qb[(size_t)(q0 + m) * HD + quad * 8];
    short8 qb = *(const short8*)&Qb[(size_t)(q0 + 16 + m) * HD + quad * 8];

    floatx4 oa0 = {}, oa1 = {}, ob0 = {}, ob1 = {};
    floatx4 la = {}, lb = {};                 // row-sum accumulators (MFMA pipe)

    short8 ones = {16256, 16256, 16256, 16256, 16256, 16256, 16256, 16256}; // bf16 1.0
    union PW { unsigned int u[4]; short8 s8; };

    // preload chunks 0 (A regs) and 1 (B regs)
    short8 ka0 = *(const short8*)&Kb[(size_t)m * HD + quad * 8];
    short8 ka1 = *(const short8*)&Kb[(size_t)(m + 16) * HD + quad * 8];
    short8 va0 = *(const short8*)&Vtb[(size_t)m * S + quad * 8];
    short8 va1 = *(const short8*)&Vtb[(size_t)(m + 16) * S + quad * 8];
    short8 kb0 = *(const short8*)&Kb[(size_t)(32 + m) * HD + quad * 8];
    short8 kb1 = *(const short8*)&Kb[(size_t)(48 + m) * HD + quad * 8];
    short8 vb0 = *(const short8*)&Vtb[(size_t)m * S + 32 + quad * 8];
    short8 vb1 = *(const short8*)&Vtb[(size_t)(m + 16) * S + 32 + quad * 8];

    for (int i = 0; i < S / 32; i += 2) {
        floatx4 z = {};
        // ---- chunk i (A): swapped QK^T, then K prefetch i+2 into freed regs
        floatx4 taa0 = __builtin_amdgcn_mfma_f32_16x16x32_bf16(ka0, qa, z, 0, 0, 0);
        floatx4 taa1 = __builtin_amdgcn_mfma_f32_16x16x32_bf16(ka1, qa, z, 0, 0, 0);
        floatx4 tab0 = __builtin_amdgcn_mfma_f32_16x16x32_bf16(ka0, qb, z, 0, 0, 0);
        floatx4 tab1 = __builtin_amdgcn_mfma_f32_16x16x32_bf16(ka1, qb, z, 0, 0, 0);
        int kA = ((i + 2) * 32) & (S - 1);
        ka0 = *(const short8*)&Kb[(size_t)(kA + m) * HD + quad * 8];
        ka1 = *(const short8*)&Kb[(size_t)(kA + m + 16) * HD + quad * 8];

        // ---- chunk i+1 (B): swapped QK^T, K prefetch i+3
        floatx4 tba0 = __builtin_amdgcn_mfma_f32_16x16x32_bf16(kb0, qa, z, 0, 0, 0);
        floatx4 tba1 = __builtin_amdgcn_mfma_f32_16x16x32_bf16(kb1, qa, z, 0, 0, 0);
        floatx4 tbb0 = __builtin_amdgcn_mfma_f32_16x16x32_bf16(kb0, qb, z, 0, 0, 0);
        floatx4 tbb1 = __builtin_amdgcn_mfma_f32_16x16x32_bf16(kb1, qb, z, 0, 0, 0);
        int kB = ((i + 3) * 32) & (S - 1);
        kb0 = *(const short8*)&Kb[(size_t)(kB + m) * HD + quad * 8];
        kb1 = *(const short8*)&Kb[(size_t)(kB + m + 16) * HD + quad * 8];

        // ---- A: exp2 / pack / in-register transpose
        float a0 = __builtin_amdgcn_exp2f(taa0[0]), a1 = __builtin_amdgcn_exp2f(taa0[1]);
        float a2 = __builtin_amdgcn_exp2f(taa0[2]), a3 = __builtin_amdgcn_exp2f(taa0[3]);
        float a4 = __builtin_amdgcn_exp2f(taa1[0]), a5 = __builtin_amdgcn_exp2f(taa1[1]);
        float a6 = __builtin_amdgcn_exp2f(taa1[2]), a7 = __builtin_amdgcn_exp2f(taa1[3]);
        float b0 = __builtin_amdgcn_exp2f(tab0[0]), b1 = __builtin_amdgcn_exp2f(tab0[1]);
        float b2 = __builtin_amdgcn_exp2f(tab0[2]), b3 = __builtin_amdgcn_exp2f(tab0[3]);
        float b4 = __builtin_amdgcn_exp2f(tab1[0]), b5 = __builtin_amdgcn_exp2f(tab1[1]);
        float b6 = __builtin_amdgcn_exp2f(tab1[2]), b7 = __builtin_amdgcn_exp2f(tab1[3]);
        unsigned int waa0, waa1, waa2, waa3, wab0, wab1, wab2, wab3;
        asm("v_cvt_pk_bf16_f32 %0, %1, %2" : "=v"(waa0) : "v"(a0), "v"(a1));
        asm("v_cvt_pk_bf16_f32 %0, %1, %2" : "=v"(waa1) : "v"(a2), "v"(a3));
        asm("v_cvt_pk_bf16_f32 %0, %1, %2" : "=v"(waa2) : "v"(a4), "v"(a5));
        asm("v_cvt_pk_bf16_f32 %0, %1, %2" : "=v"(waa3) : "v"(a6), "v"(a7));
        asm("v_cvt_pk_bf16_f32 %0, %1, %2" : "=v"(wab0) : "v"(b0), "v"(b1));
        asm("v_cvt_pk_bf16_f32 %0, %1, %2" : "=v"(wab1) : "v"(b2), "v"(b3));
        asm("v_cvt_pk_bf16_f32 %0, %1, %2" : "=v"(wab2) : "v"(b4), "v"(b5));
        asm("v_cvt_pk_bf16_f32 %0, %1, %2" : "=v"(wab3) : "v"(b6), "v"(b7));
        asm("v_permlane32_swap_b32 %0, %1" : "+v"(waa0), "+v"(waa2));
        asm("v_permlane32_swap_b32 %0, %1" : "+v"(waa1), "+v"(waa3));
        asm("v_permlane16_swap_b32 %0, %1" : "+v"(waa0), "+v"(waa2));
        asm("v_permlane16_swap_b32 %0, %1" : "+v"(waa1), "+v"(waa3));
        asm("v_permlane32_swap_b32 %0, %1" : "+v"(wab0), "+v"(wab2));
        asm("v_permlane32_swap_b32 %0, %1" : "+v"(wab1), "+v"(wab3));
        asm("v_permlane16_swap_b32 %0, %1" : "+v"(wab0), "+v"(wab2));
        asm("v_permlane16_swap_b32 %0, %1" : "+v"(wab1), "+v"(wab3));
        PW pwaa, pwab;
        pwaa.u[0] = waa0; pwaa.u[1] = waa1; pwaa.u[2] = waa2; pwaa.u[3] = waa3;
        pwab.u[0] = wab0; pwab.u[1] = wab1; pwab.u[2] = wab2; pwab.u[3] = wab3;

        // ---- A: PV + l, then V prefetch i+2 into freed regs
        oa0 = __builtin_amdgcn_mfma_f32_16x16x32_bf16(pwaa.s8, va0, oa0, 0, 0, 0);
        oa1 = __builtin_amdgcn_mfma_f32_16x16x32_bf16(pwaa.s8, va1, oa1, 0, 0, 0);
        la  = __builtin_amdgcn_mfma_f32_16x16x32_bf16(pwaa.s8, ones, la, 0, 0, 0);
        ob0 = __builtin_amdgcn_mfma_f32_16x16x32_bf16(pwab.s8, va0, ob0, 0, 0, 0);
        ob1 = __builtin_amdgcn_mfma_f32_16x16x32_bf16(pwab.s8, va1, ob1, 0, 0, 0);
        lb  = __builtin_amdgcn_mfma_f32_16x16x32_bf16(pwab.s8, ones, lb, 0, 0, 0);
        va0 = *(const short8*)&Vtb[(size_t)m * S + kA + quad * 8];
        va1 = *(const short8*)&Vtb[(size_t)(m + 16) * S + kA + quad * 8];

        // ---- B: exp2 / pack / transpose (overlaps A's PV on the VALU pipe)
        float c0 = __builtin_amdgcn_exp2f(tba0[0]), c1 = __builtin_amdgcn_exp2f(tba0[1]);
        float c2 = __builtin_amdgcn_exp2f(tba0[2]), c3 = __builtin_amdgcn_exp2f(tba0[3]);
        float c4 = __builtin_amdgcn_exp2f(tba1[0]), c5 = __builtin_amdgcn_exp2f(tba1[1]);
        float c6 = __builtin_amdgcn_exp2f(tba1[2]), c7 = __builtin_amdgcn_exp2f(tba1[3]);
        float d0 = __builtin_amdgcn_exp2f(tbb0[0]), d1 = __builtin_amdgcn_exp2f(tbb0[1]);
        float d2 = __builtin_amdgcn_exp2f(tbb0[2]), d3 = __builtin_amdgcn_exp2f(tbb0[3]);
        float d4 = __builtin_amdgcn_exp2f(tbb1[0]), d5 = __builtin_amdgcn_exp2f(tbb1[1]);
        float d6 = __builtin_amdgcn_exp2f(tbb1[2]), d7 = __builtin_amdgcn_exp2f(tbb1[3]);
        unsigned int wba0, wba1, wba2, wba3, wbb0, wbb1, wbb2, wbb3;
        asm("v_cvt_pk_bf16_f32 %0, %1, %2" : "=v"(wba0) : "v"(c0), "v"(c1));
        asm("v_cvt_pk_bf16_f32 %0, %1, %2" : "=v"(wba1) : "v"(c2), "v"(c3));
        asm("v_cvt_pk_bf16_f32 %0, %1, %2" : "=v"(wba2) : "v"(c4), "v"(c5));
        asm("v_cvt_pk_bf16_f32 %0, %1, %2" : "=v"(wba3) : "v"(c6), "v"(c7));
        asm("v_cvt_pk_bf16_f32 %0, %1, %2" : "=v"(wbb0) : "v"(d0), "v"(d1));
        asm("v_cvt_pk_bf16_f32 %0, %1, %2" : "=v"(wbb1) : "v"(d2), "v"(d3));
        asm("v_cvt_pk_bf16_f32 %0, %1, %2" : "=v"(wbb2) : "v"(d4), "v"(d5));
        asm("v_cvt_pk_bf16_f32 %0, %1, %2" : "=v"(wbb3) : "v"(d6), "v"(d7));
        asm("v_permlane32_swap_b32 %0, %1" : "+v"(wba0), "+v"(wba2));
        asm("v_permlane32_swap_b32 %0, %1" : "+v"(wba1), "+v"(wba3));
        asm("v_permlane16_swap_b32 %0, %1" : "+v"(wba0), "+v"(wba2));
        asm("v_permlane16_swap_b32 %0, %1" : "+v"(wba1), "+v"(wba3));
        asm("v_permlane32_swap_b32 %0, %1" : "+v"(wbb0), "+v"(wbb2));
        asm("v_permlane32_swap_b32 %0, %1" : "+v"(wbb1), "+v"(wbb3));
        asm("v_permlane16_swap_b32 %0, %1" : "+v"(wbb0), "+v"(wbb2));
        asm("v_permlane16_swap_b32 %0, %1" : "+v"(wbb1), "+v"(wbb3));
        PW pwba, pwbb;
        pwba.u[0] = wba0; pwba.u[1] = wba1; pwba.u[2] = wba2; pwba.u[3] = wba3;
        pwbb.u[0] = wbb0; pwbb.u[1] = wbb1; pwbb.u[2] = wbb2; pwbb.u[3] = wbb3;

        // ---- B: PV + l, then V prefetch i+3
        oa0 = __builtin_amdgcn_mfma_f32_16x16x32_bf16(pwba.s8, vb0, oa0, 0, 0, 0);
        oa1 = __builtin_amdgcn_mfma_f32_16x16x32_bf16(pwba.s8, vb1, oa1, 0, 0, 0);
        la  = __builtin_amdgcn_mfma_f32_16x16x32_bf16(pwba.s8, ones, la, 0, 0, 0);
        ob0 = __builtin_amdgcn_mfma_f32_16x16x32_bf16(pwbb.s8, vb0, ob0, 0, 0, 0);
        ob1 = __builtin_amdgcn_mfma_f32_16x16x32_bf16(pwbb.s8, vb1, ob1, 0, 0, 0);
        lb  = __builtin_amdgcn_mfma_f32_16x16x32_bf16(pwbb.s8, ones, lb, 0, 0, 0);
        vb0 = *(const short8*)&Vtb[(size_t)m * S + kB + quad * 8];
        vb1 = *(const short8*)&Vtb[(size_t)(m + 16) * S + kB + quad * 8];
    }

    // epilogue: l is row-aligned with O (row = quad*4+r), no shuffles
    int batch = bh >> 2, head = bh & 3;
    int grow = batch * S + q0 + quad * 4;
    int col = head * HD + m;
#pragma unroll
    for (int r = 0; r < 4; r++) {
        float iar = 1.f / la[r], ibr = 1.f / lb[r];
        Ob[(size_t)(grow + r) * H + col]           = f32_to_bf16(oa0[r] * iar);
        Ob[(size_t)(grow + r) * H + col + 16]      = f32_to_bf16(oa1[r] * iar);
        Ob[(size_t)(grow + 16 + r) * H + col]      = f32_to_bf16(ob0[r] * ibr);
        Ob[(size_t)(grow + 16 + r) * H + col + 16] = f32_to_bf16(ob1[r] * ibr);
    }
}

// ---------- output projection GEMM (N=128) + bias, dual-dtype store ----------
__global__ __launch_bounds__(256) void mmout_kernel(const unsigned short* __restrict__ A,
        const unsigned short* __restrict__ B, const float* __restrict__ bias,
        void* __restrict__ out, const int* __restrict__ flags) {
    int tid = threadIdx.x, wave = tid >> 6, lane = tid & 63, m = lane & 15, quad = lane >> 4;
    int row0 = blockIdx.x * 64 + wave * 16;
    floatx4 acc[8] = {};
    for (int kc = 0; kc < H; kc += 32) {
        short8 af = *(const short8*)&A[(size_t)(row0 + m) * H + kc + quad * 8];
#pragma unroll
        for (int t = 0; t < 8; t++) {
            short8 bf = *(const short8*)&B[(size_t)(t * 16 + m) * H + kc + quad * 8];
            acc[t] = __builtin_amdgcn_mfma_f32_16x16x32_bf16(af, bf, acc[t], 0, 0, 0);
        }
    }
    int rbase = row0 + quad * 4;
    int f32o = flags[0];
#pragma unroll
    for (int t = 0; t < 8; t++) {
        int col = t * 16 + m;
        float bj = bias[col];
#pragma unroll
        for (int r = 0; r < 4; r++) {
            float v = acc[t][r] + bj;
            if (f32o) ((float*)out)[(size_t)(rbase + r) * H + col] = v;
            else ((unsigned short*)out)[(size_t)(rbase + r) * H + col] = f32_to_bf16(v);
        }
    }
}

extern "C" void kernel_launch(void* const* d_in, const int* in_sizes, int n_in,
                              void* d_out, int out_size, void* d_ws, size_t ws_size,
                              hipStream_t stream) {
    const void* x_raw    = d_in[0];
    const int*  ei_raw   = (const int*)d_in[1];
    const void* W1_raw   = d_in[2];
    const void* b1_raw   = d_in[3];
    const void* W2_raw   = d_in[4];
    const void* b2_raw   = d_in[5];
    const void* Wq_raw   = d_in[6];
    const void* bq_raw   = d_in[7];
    const void* Wo_raw   = d_in[8];
    const void* bo_raw   = d_in[9];

    char* ws = (char*)d_ws;
    size_t o = 0;
    auto alloc = [&](size_t bytes) { void* p = ws + o; o += (bytes + 1023) & ~1023ull; return p; };

    int*   flags     = (int*)  alloc(1024);
    int*   cnt       = (int*)  alloc((size_t)GN * 4);
    int*   row_start = (int*)  alloc((size_t)GN * 4);
    int*   fill_pos  = (int*)  alloc((size_t)GN * 4);
    float* dinv      = (float*)alloc((size_t)GN * 4);
    int*   srcA      = (int*)  alloc((size_t)ETOT * 4);
    int*   dstA      = (int*)  alloc((size_t)ETOT * 4);
    int*   csr_src   = (int*)  alloc((size_t)ETOT * 4);
    unsigned short* xb   = (unsigned short*)alloc((size_t)GN * CIN * 2);
    unsigned short* W1T  = (unsigned short*)alloc((size_t)H * CIN * 2);
    unsigned short* W2T  = (unsigned short*)alloc((size_t)H * H * 2);
    unsigned short* Wqb  = (unsigned short*)alloc((size_t)QKV * H * 2);
    unsigned short* Wob  = (unsigned short*)alloc((size_t)H * H * 2);
    float* b1f = (float*)alloc(H * 4);
    float* b2f = (float*)alloc(H * 4);
    float* bqf = (float*)alloc(QKV * 4);
    float* bof = (float*)alloc(H * 4);
    unsigned short* y_bf = (unsigned short*)alloc((size_t)GN * H * 2);
    unsigned short* h_bf = (unsigned short*)alloc((size_t)GN * H * 2);
    unsigned short* Qx   = (unsigned short*)alloc((size_t)16 * S * HD * 2);
    unsigned short* Kx   = (unsigned short*)alloc((size_t)16 * S * HD * 2);
    unsigned short* Vtx  = (unsigned short*)alloc((size_t)16 * S * HD * 2);
    unsigned short* Obf  = y_bf;   // y dead after second agg

    detect_kernel<<<1, 256, 0, stream>>>((const unsigned short*)x_raw, ei_raw, flags);

    conv_all_kernel<<<(CTOT + 255) / 256, 256, 0, stream>>>(
        x_raw, W1_raw, b1_raw, W2_raw, b2_raw, Wq_raw, bq_raw, Wo_raw, bo_raw,
        xb, W1T, W2T, Wqb, Wob, b1f, b2f, bqf, bof, flags);

    edges_kernel<<<ETOT / 256, 256, 0, stream>>>(ei_raw, srcA, dstA, flags);
    hipMemsetAsync(cnt, 0, (size_t)GN * 4, stream);
    count_kernel<<<ETOT / 256, 256, 0, stream>>>(dstA, cnt);
    scan_kernel<<<G, NPG, 0, stream>>>(cnt, row_start, fill_pos, dinv);
    fill_kernel<<<ETOT / 256, 256, 0, stream>>>(srcA, dstA, fill_pos, csr_src);

    // GCN layer 1
    mm_gcn_kernel<CIN><<<GN / 64, 256, 0, stream>>>(xb, W1T, dinv, y_bf);
    agg_kernel<<<GN, H, 0, stream>>>(y_bf, row_start, cnt, csr_src, dinv, b1f, h_bf);
    // GCN layer 2
    mm_gcn_kernel<H><<<GN / 64, 256, 0, stream>>>(h_bf, W2T, dinv, y_bf);
    agg_kernel<<<GN, H, 0, stream>>>(y_bf, row_start, cnt, csr_src, dinv, b2f, h_bf);

    // attention
    mmqkv_kernel<<<GN / 64, 256, 0, stream>>>(h_bf, Wqb, bqf, Qx, Kx, Vtx);
    attn6_kernel<<<dim3(512), 256, 0, stream>>>(Qx, Kx, Vtx, Obf);
    mmout_kernel<<<GN / 64, 256, 0, stream>>>(Obf, Wob, bof, d_out, flags);
}

// Round 4
// 270.037 us; speedup vs baseline: 1.3061x; 1.0165x over previous
//
#include <hip/hip_runtime.h>
#include <hip/hip_bf16.h>

#define G     32
#define NPG   512
#define EPG   8192
#define GN    16384        // G*NPG
#define ETOT  (G*EPG)      // 262144
#define CIN   64
#define H     128
#define NB    4
#define S     4096         // T*NPG
#define HEADS 4
#define HD    32
#define QKV   384

typedef __attribute__((ext_vector_type(8))) short short8;
typedef __attribute__((ext_vector_type(4))) float floatx4;

__device__ __forceinline__ float bf16_to_f32(unsigned short u) {
    unsigned int x = ((unsigned int)u) << 16;
    return __uint_as_float(x);
}
__device__ __forceinline__ unsigned short f32_to_bf16(float f) {
    __hip_bfloat16 h = (__hip_bfloat16)f;
    return *(unsigned short*)&h;
}
__device__ __forceinline__ float ldf(const void* p, long i, int f32) {
    return f32 ? ((const float*)p)[i] : bf16_to_f32(((const unsigned short*)p)[i]);
}

// ---------- runtime dtype detection ----------
__global__ void detect_kernel(const unsigned short* __restrict__ xraw,
                              const int* __restrict__ eiraw, int* __restrict__ flags) {
    __shared__ float smax[256];
    __shared__ int   sor[256];
    int t = threadIdx.x;
    float m = 0.f;
    for (int i = t; i < 4096; i += 256)
        m = fmaxf(m, fabsf(bf16_to_f32(xraw[i])));
    int orv = 0;
    for (int i = t; i < 2048; i += 256)
        orv |= eiraw[2 * i + 1];
    smax[t] = m; sor[t] = orv;
    __syncthreads();
    for (int off = 128; off > 0; off >>= 1) {
        if (t < off) {
            smax[t] = fmaxf(smax[t], smax[t + off]);
            sor[t] |= sor[t + off];
        }
        __syncthreads();
    }
    if (t == 0) {
        flags[0] = (smax[0] > 1000.f) ? 1 : 0;
        flags[1] = (sor[0] == 0) ? 1 : 0;
    }
}

// ---------- fused conversion: everything -> bf16 (weights pre-transposed) ----------
#define XN   (GN*CIN)          // x:      [0,      XN)
#define E1   (XN + H*CIN)      // W1T
#define E2   (E1 + H*H)        // W2T
#define E3   (E2 + QKV*H)      // Wqkv
#define E4   (E3 + H*H)        // Wo
#define E5   (E4 + H)          // b1
#define E6   (E5 + H)          // b2
#define E7   (E6 + QKV)        // bqkv
#define CTOT (E7 + H)          // bo
__global__ void conv_all_kernel(const void* x_raw, const void* W1_raw, const void* b1_raw,
                                const void* W2_raw, const void* b2_raw, const void* Wq_raw,
                                const void* bq_raw, const void* Wo_raw, const void* bo_raw,
                                unsigned short* __restrict__ xb,
                                unsigned short* __restrict__ W1T,
                                unsigned short* __restrict__ W2T,
                                unsigned short* __restrict__ Wqb,
                                unsigned short* __restrict__ Wob,
                                float* __restrict__ b1f, float* __restrict__ b2f,
                                float* __restrict__ bqf, float* __restrict__ bof,
                                const int* __restrict__ flags) {
    int i = blockIdx.x * blockDim.x + threadIdx.x;
    if (i >= CTOT) return;
    int f32 = flags[0];
    if (i < XN) {
        xb[i] = f32_to_bf16(ldf(x_raw, i, f32));
    } else if (i < E1) {       // W1T[c][r] = W1[r][c], [H out][CIN in]
        int j = i - XN, c = j / CIN, r = j - c * CIN;
        W1T[j] = f32_to_bf16(ldf(W1_raw, (long)r * H + c, f32));
    } else if (i < E2) {       // W2T[c][r] = W2[r][c]
        int j = i - E1, c = j >> 7, r = j & 127;
        W2T[j] = f32_to_bf16(ldf(W2_raw, (long)r * H + c, f32));
    } else if (i < E3) {       // in_proj_w already [out][in]
        int j = i - E2;
        Wqb[j] = f32_to_bf16(ldf(Wq_raw, j, f32));
    } else if (i < E4) {
        int j = i - E3;
        Wob[j] = f32_to_bf16(ldf(Wo_raw, j, f32));
    } else if (i < E5) { b1f[i - E4] = ldf(b1_raw, i - E4, f32); }
    else if (i < E6) { b2f[i - E5] = ldf(b2_raw, i - E5, f32); }
    else if (i < E7) { bqf[i - E6] = ldf(bq_raw, i - E6, f32); }
    else             { bof[i - E7] = ldf(bo_raw, i - E7, f32); }
}

// ---------- edges / CSR ----------
__global__ void edges_kernel(const int* __restrict__ ei, int* __restrict__ srcA,
                             int* __restrict__ dstA, const int* __restrict__ flags) {
    int t = blockIdx.x * blockDim.x + threadIdx.x;
    if (t >= ETOT) return;
    int g = t >> 13, e = t & (EPG - 1);
    int sh = flags[1];
    long long si = ((long long)(g * 2 + 0) * EPG + e) << sh;
    long long di = ((long long)(g * 2 + 1) * EPG + e) << sh;
    srcA[t] = g * NPG + ei[si];
    dstA[t] = g * NPG + ei[di];
}

__global__ void count_kernel(const int* __restrict__ dstA, int* __restrict__ cnt) {
    int t = blockIdx.x * blockDim.x + threadIdx.x;
    if (t >= ETOT) return;
    atomicAdd(&cnt[dstA[t]], 1);
}

__global__ void scan_kernel(const int* __restrict__ cnt, int* __restrict__ row_start,
                            int* __restrict__ fill_pos, float* __restrict__ dinv) {
    __shared__ int tmp[NPG];
    int g = blockIdx.x, t = threadIdx.x;
    int c = cnt[g * NPG + t];
    tmp[t] = c;
    __syncthreads();
    for (int off = 1; off < NPG; off <<= 1) {
        int v = (t >= off) ? tmp[t - off] : 0;
        __syncthreads();
        tmp[t] += v;
        __syncthreads();
    }
    int excl = tmp[t] - c;
    int rs = g * EPG + excl;
    row_start[g * NPG + t] = rs;
    fill_pos[g * NPG + t]  = rs;
    dinv[g * NPG + t] = 1.0f / sqrtf((float)c + 1.0f);
}

__global__ void fill_kernel(const int* __restrict__ srcA, const int* __restrict__ dstA,
                            int* __restrict__ fill_pos, int* __restrict__ csr_src) {
    int t = blockIdx.x * blockDim.x + threadIdx.x;
    if (t >= ETOT) return;
    int pos = atomicAdd(&fill_pos[dstA[t]], 1);
    csr_src[pos] = srcA[t];
}

// ---------- MFMA GEMM: Y[row][col] = (A[row][:] . B[col][:]) * dinv[row]  (bf16 out)
template<int KD>
__global__ __launch_bounds__(256) void mm_gcn_kernel(const unsigned short* __restrict__ A,
        const unsigned short* __restrict__ B, const float* __restrict__ dinv,
        unsigned short* __restrict__ Y) {
    int tid = threadIdx.x, wave = tid >> 6, lane = tid & 63, m = lane & 15, quad = lane >> 4;
    int row0 = blockIdx.x * 64 + wave * 16;
    floatx4 acc[8] = {};
    for (int kc = 0; kc < KD; kc += 32) {
        short8 af = *(const short8*)&A[(size_t)(row0 + m) * KD + kc + quad * 8];
#pragma unroll
        for (int t = 0; t < 8; t++) {
            short8 bf = *(const short8*)&B[(size_t)(t * 16 + m) * KD + kc + quad * 8];
            acc[t] = __builtin_amdgcn_mfma_f32_16x16x32_bf16(af, bf, acc[t], 0, 0, 0);
        }
    }
    int rbase = row0 + quad * 4;
    float4 dv4 = *(const float4*)&dinv[rbase];
    float dv[4] = {dv4.x, dv4.y, dv4.z, dv4.w};
#pragma unroll
    for (int t = 0; t < 8; t++) {
        int col = t * 16 + m;
#pragma unroll
        for (int r = 0; r < 4; r++)
            Y[(size_t)(rbase + r) * H + col] = f32_to_bf16(acc[t][r] * dv[r]);
    }
}

// ---------- GCN aggregation (bf16 in/out, f32 accum), gather unrolled x4 ----------
__global__ void agg_kernel(const unsigned short* __restrict__ y,
                           const int* __restrict__ row_start, const int* __restrict__ cnt,
                           const int* __restrict__ csr_src, const float* __restrict__ dinv,
                           const float* __restrict__ bias, unsigned short* __restrict__ hout) {
    int i = blockIdx.x;
    int c = threadIdx.x;
    float acc = bf16_to_f32(y[(size_t)i * H + c]);   // self-loop
    int rs = row_start[i], n = cnt[i];
    int p = 0;
    for (; p + 4 <= n; p += 4) {
        int s0 = csr_src[rs + p + 0];
        int s1 = csr_src[rs + p + 1];
        int s2 = csr_src[rs + p + 2];
        int s3 = csr_src[rs + p + 3];
        float a0 = bf16_to_f32(y[(size_t)s0 * H + c]);
        float a1 = bf16_to_f32(y[(size_t)s1 * H + c]);
        float a2 = bf16_to_f32(y[(size_t)s2 * H + c]);
        float a3 = bf16_to_f32(y[(size_t)s3 * H + c]);
        acc += (a0 + a1) + (a2 + a3);
    }
    for (; p < n; p++)
        acc += bf16_to_f32(y[(size_t)csr_src[rs + p] * H + c]);
    hout[(size_t)i * H + c] = f32_to_bf16(acc * dinv[i] + bias[c]);
}

// ---------- QKV GEMM (N=384) with blocked epilogue ----------
// Q pre-scale folds log2(e) so attention can use raw v_exp_f32 (2^x).
__global__ __launch_bounds__(256) void mmqkv_kernel(const unsigned short* __restrict__ A,
        const unsigned short* __restrict__ B, const float* __restrict__ bias,
        unsigned short* __restrict__ Qx, unsigned short* __restrict__ Kx,
        unsigned short* __restrict__ Vtx) {
    int tid = threadIdx.x, wave = tid >> 6, lane = tid & 63, m = lane & 15, quad = lane >> 4;
    int row0 = blockIdx.x * 64 + wave * 16;
    floatx4 acc[24] = {};
    for (int kc = 0; kc < H; kc += 32) {
        short8 af = *(const short8*)&A[(size_t)(row0 + m) * H + kc + quad * 8];
#pragma unroll
        for (int t = 0; t < 24; t++) {
            short8 bf = *(const short8*)&B[(size_t)(t * 16 + m) * H + kc + quad * 8];
            acc[t] = __builtin_amdgcn_mfma_f32_16x16x32_bf16(af, bf, acc[t], 0, 0, 0);
        }
    }
    int rbase = row0 + quad * 4;                    // rows rbase..rbase+3, same batch
    int b = rbase >> 12, s0 = rbase & (S - 1);
#pragma unroll
    for (int t = 0; t < 24; t++) {
        int j = t * 16 + m;                         // 0..383
        float bj = bias[j];
        int jj = j & 127, head = jj >> 5, hd = jj & 31;
        int bh = b * HEADS + head;
        if (t < 8) {                                // Q (pre-scaled by log2e/sqrt(hd))
#pragma unroll
            for (int r = 0; r < 4; r++)
                Qx[((size_t)bh * S + s0 + r) * HD + hd] =
                    f32_to_bf16((acc[t][r] + bj) *
                                (0.17677669529663687f * 1.4426950408889634f));
        } else if (t < 16) {                        // K
#pragma unroll
            for (int r = 0; r < 4; r++)
                Kx[((size_t)bh * S + s0 + r) * HD + hd] = f32_to_bf16(acc[t][r] + bj);
        } else {                                    // V transposed
#pragma unroll
            for (int r = 0; r < 4; r++)
                Vtx[((size_t)bh * HD + hd) * S + s0 + r] = f32_to_bf16(acc[t][r] + bj);
        }
    }
}

// ---------- MFMA flash attention v7: 64 q-rows/wave to amortize the fixed
// per-chunk latency (~780 cy measured invariant across attn4/5/6: wall =
// wave-chunks x (778 + 66*tiles) cy, independent of resident waves).
// 4 q-tiles/wave: per 32-k chunk = 8 QK MFMA + 32 exp + 16 cvt + 16 permlane
// + 12 PV/l MFMA against the same 4 K/V loads.  Zero LDS, in-register P
// transpose, l on the MFMA pipe.  XCD swizzle keeps 2 bh-streams per XCD-L2.
// grid 256 (1 block/CU, 1 wave/SIMD), block 256.
__global__ __launch_bounds__(256) void attn7_kernel(
        const unsigned short* __restrict__ Qx, const unsigned short* __restrict__ Kx,
        const unsigned short* __restrict__ Vtx, unsigned short* __restrict__ Ob) {
    int tid = threadIdx.x, wave = tid >> 6, lane = tid & 63;
    int m = lane & 15, quad = lane >> 4;

    int n = blockIdx.x;                       // 0..255, XCD ~ n%8
    int id = (n & 7) * 32 + (n >> 3);         // XCD x owns ids [32x,32x+32) -> bh {2x,2x+1}
    int tile = id & 15, bh = id >> 4;

    const unsigned short* Qb  = Qx  + (size_t)bh * S * HD;
    const unsigned short* Kb  = Kx  + (size_t)bh * S * HD;
    const unsigned short* Vtb = Vtx + (size_t)bh * HD * S;

    int q0 = tile * 256 + wave * 64;
    short8 q[4];
#pragma unroll
    for (int t = 0; t < 4; t++)
        q[t] = *(const short8*)&Qb[(size_t)(q0 + t * 16 + m) * HD + quad * 8];

    floatx4 o0[4] = {}, o1[4] = {}, l[4] = {};

    short8 ones = {16256, 16256, 16256, 16256, 16256, 16256, 16256, 16256}; // bf16 1.0
    union PW { unsigned int u[4]; short8 s8; };

    // chunk 0 K/V
    short8 kf0 = *(const short8*)&Kb[(size_t)m * HD + quad * 8];
    short8 kf1 = *(const short8*)&Kb[(size_t)(m + 16) * HD + quad * 8];
    short8 vc0 = *(const short8*)&Vtb[(size_t)m * S + quad * 8];
    short8 vc1 = *(const short8*)&Vtb[(size_t)(m + 16) * S + quad * 8];

    for (int i = 0; i < S / 32; i++) {
        floatx4 z = {};
        // swapped QK^T for all 4 q-tiles (lane(m,quad): P^T[k=quad*4+r][q=m])
        floatx4 t0[4], t1[4];
#pragma unroll
        for (int t = 0; t < 4; t++) {
            t0[t] = __builtin_amdgcn_mfma_f32_16x16x32_bf16(kf0, q[t], z, 0, 0, 0);
            t1[t] = __builtin_amdgcn_mfma_f32_16x16x32_bf16(kf1, q[t], z, 0, 0, 0);
        }
        // K prefetch for chunk i+1 (used at top of next iter, ~full iter ahead)
        int ktn = ((i + 1) * 32) & (S - 1);
        kf0 = *(const short8*)&Kb[(size_t)(ktn + m) * HD + quad * 8];
        kf1 = *(const short8*)&Kb[(size_t)(ktn + m + 16) * HD + quad * 8];

        // exp2 -> pack bf16 -> in-register transpose, per tile
        PW pw[4];
#pragma unroll
        for (int t = 0; t < 4; t++) {
            float e0 = __builtin_amdgcn_exp2f(t0[t][0]);
            float e1 = __builtin_amdgcn_exp2f(t0[t][1]);
            float e2 = __builtin_amdgcn_exp2f(t0[t][2]);
            float e3 = __builtin_amdgcn_exp2f(t0[t][3]);
            float e4 = __builtin_amdgcn_exp2f(t1[t][0]);
            float e5 = __builtin_amdgcn_exp2f(t1[t][1]);
            float e6 = __builtin_amdgcn_exp2f(t1[t][2]);
            float e7 = __builtin_amdgcn_exp2f(t1[t][3]);
            unsigned int w0, w1, w2, w3;
            asm("v_cvt_pk_bf16_f32 %0, %1, %2" : "=v"(w0) : "v"(e0), "v"(e1));
            asm("v_cvt_pk_bf16_f32 %0, %1, %2" : "=v"(w1) : "v"(e2), "v"(e3));
            asm("v_cvt_pk_bf16_f32 %0, %1, %2" : "=v"(w2) : "v"(e4), "v"(e5));
            asm("v_cvt_pk_bf16_f32 %0, %1, %2" : "=v"(w3) : "v"(e6), "v"(e7));
            asm("v_permlane32_swap_b32 %0, %1" : "+v"(w0), "+v"(w2));
            asm("v_permlane32_swap_b32 %0, %1" : "+v"(w1), "+v"(w3));
            asm("v_permlane16_swap_b32 %0, %1" : "+v"(w0), "+v"(w2));
            asm("v_permlane16_swap_b32 %0, %1" : "+v"(w1), "+v"(w3));
            pw[t].u[0] = w0; pw[t].u[1] = w1; pw[t].u[2] = w2; pw[t].u[3] = w3;
        }

        // PV + row-sum l (MFMA pipe), then V prefetch for chunk i+1
#pragma unroll
        for (int t = 0; t < 4; t++) {
            o0[t] = __builtin_amdgcn_mfma_f32_16x16x32_bf16(pw[t].s8, vc0, o0[t], 0, 0, 0);
            o1[t] = __builtin_amdgcn_mfma_f32_16x16x32_bf16(pw[t].s8, vc1, o1[t], 0, 0, 0);
            l[t]  = __builtin_amdgcn_mfma_f32_16x16x32_bf16(pw[t].s8, ones, l[t], 0, 0, 0);
        }
        vc0 = *(const short8*)&Vtb[(size_t)m * S + ktn + quad * 8];
        vc1 = *(const short8*)&Vtb[(size_t)(m + 16) * S + ktn + quad * 8];
    }

    // epilogue: l is row-aligned with O (row = quad*4+r), no shuffles
    int batch = bh >> 2, head = bh & 3;
    int col = head * HD + m;
#pragma unroll
    for (int t = 0; t < 4; t++) {
        int grow = batch * S + q0 + t * 16 + quad * 4;
#pragma unroll
        for (int r = 0; r < 4; r++) {
            float inv = 1.f / l[t][r];
            Ob[(size_t)(grow + r) * H + col]      = f32_to_bf16(o0[t][r] * inv);
            Ob[(size_t)(grow + r) * H + col + 16] = f32_to_bf16(o1[t][r] * inv);
        }
    }
}

// ---------- output projection GEMM (N=128) + bias, dual-dtype store ----------
__global__ __launch_bounds__(256) void mmout_kernel(const unsigned short* __restrict__ A,
        const unsigned short* __restrict__ B, const float* __restrict__ bias,
        void* __restrict__ out, const int* __restrict__ flags) {
    int tid = threadIdx.x, wave = tid >> 6, lane = tid & 63, m = lane & 15, quad = lane >> 4;
    int row0 = blockIdx.x * 64 + wave * 16;
    floatx4 acc[8] = {};
    for (int kc = 0; kc < H; kc += 32) {
        short8 af = *(const short8*)&A[(size_t)(row0 + m) * H + kc + quad * 8];
#pragma unroll
        for (int t = 0; t < 8; t++) {
            short8 bf = *(const short8*)&B[(size_t)(t * 16 + m) * H + kc + quad * 8];
            acc[t] = __builtin_amdgcn_mfma_f32_16x16x32_bf16(af, bf, acc[t], 0, 0, 0);
        }
    }
    int rbase = row0 + quad * 4;
    int f32o = flags[0];
#pragma unroll
    for (int t = 0; t < 8; t++) {
        int col = t * 16 + m;
        float bj = bias[col];
#pragma unroll
        for (int r = 0; r < 4; r++) {
            float v = acc[t][r] + bj;
            if (f32o) ((float*)out)[(size_t)(rbase + r) * H + col] = v;
            else ((unsigned short*)out)[(size_t)(rbase + r) * H + col] = f32_to_bf16(v);
        }
    }
}

extern "C" void kernel_launch(void* const* d_in, const int* in_sizes, int n_in,
                              void* d_out, int out_size, void* d_ws, size_t ws_size,
                              hipStream_t stream) {
    const void* x_raw    = d_in[0];
    const int*  ei_raw   = (const int*)d_in[1];
    const void* W1_raw   = d_in[2];
    const void* b1_raw   = d_in[3];
    const void* W2_raw   = d_in[4];
    const void* b2_raw   = d_in[5];
    const void* Wq_raw   = d_in[6];
    const void* bq_raw   = d_in[7];
    const void* Wo_raw   = d_in[8];
    const void* bo_raw   = d_in[9];

    char* ws = (char*)d_ws;
    size_t o = 0;
    auto alloc = [&](size_t bytes) { void* p = ws + o; o += (bytes + 1023) & ~1023ull; return p; };

    int*   flags     = (int*)  alloc(1024);
    int*   cnt       = (int*)  alloc((size_t)GN * 4);
    int*   row_start = (int*)  alloc((size_t)GN * 4);
    int*   fill_pos  = (int*)  alloc((size_t)GN * 4);
    float* dinv      = (float*)alloc((size_t)GN * 4);
    int*   srcA      = (int*)  alloc((size_t)ETOT * 4);
    int*   dstA      = (int*)  alloc((size_t)ETOT * 4);
    int*   csr_src   = (int*)  alloc((size_t)ETOT * 4);
    unsigned short* xb   = (unsigned short*)alloc((size_t)GN * CIN * 2);
    unsigned short* W1T  = (unsigned short*)alloc((size_t)H * CIN * 2);
    unsigned short* W2T  = (unsigned short*)alloc((size_t)H * H * 2);
    unsigned short* Wqb  = (unsigned short*)alloc((size_t)QKV * H * 2);
    unsigned short* Wob  = (unsigned short*)alloc((size_t)H * H * 2);
    float* b1f = (float*)alloc(H * 4);
    float* b2f = (float*)alloc(H * 4);
    float* bqf = (float*)alloc(QKV * 4);
    float* bof = (float*)alloc(H * 4);
    unsigned short* y_bf = (unsigned short*)alloc((size_t)GN * H * 2);
    unsigned short* h_bf = (unsigned short*)alloc((size_t)GN * H * 2);
    unsigned short* Qx   = (unsigned short*)alloc((size_t)16 * S * HD * 2);
    unsigned short* Kx   = (unsigned short*)alloc((size_t)16 * S * HD * 2);
    unsigned short* Vtx  = (unsigned short*)alloc((size_t)16 * S * HD * 2);
    unsigned short* Obf  = y_bf;   // y dead after second agg

    detect_kernel<<<1, 256, 0, stream>>>((const unsigned short*)x_raw, ei_raw, flags);

    conv_all_kernel<<<(CTOT + 255) / 256, 256, 0, stream>>>(
        x_raw, W1_raw, b1_raw, W2_raw, b2_raw, Wq_raw, bq_raw, Wo_raw, bo_raw,
        xb, W1T, W2T, Wqb, Wob, b1f, b2f, bqf, bof, flags);

    edges_kernel<<<ETOT / 256, 256, 0, stream>>>(ei_raw, srcA, dstA, flags);
    hipMemsetAsync(cnt, 0, (size_t)GN * 4, stream);
    count_kernel<<<ETOT / 256, 256, 0, stream>>>(dstA, cnt);
    scan_kernel<<<G, NPG, 0, stream>>>(cnt, row_start, fill_pos, dinv);
    fill_kernel<<<ETOT / 256, 256, 0, stream>>>(srcA, dstA, fill_pos, csr_src);

    // GCN layer 1
    mm_gcn_kernel<CIN><<<GN / 64, 256, 0, stream>>>(xb, W1T, dinv, y_bf);
    agg_kernel<<<GN, H, 0, stream>>>(y_bf, row_start, cnt, csr_src, dinv, b1f, h_bf);
    // GCN layer 2
    mm_gcn_kernel<H><<<GN / 64, 256, 0, stream>>>(h_bf, W2T, dinv, y_bf);
    agg_kernel<<<GN, H, 0, stream>>>(y_bf, row_start, cnt, csr_src, dinv, b2f, h_bf);

    // attention
    mmqkv_kernel<<<GN / 64, 256, 0, stream>>>(h_bf, Wqb, bqf, Qx, Kx, Vtx);
    attn7_kernel<<<dim3(256), 256, 0, stream>>>(Qx, Kx, Vtx, Obf);
    mmout_kernel<<<GN / 64, 256, 0, stream>>>(Obf, Wob, bof, d_out, flags);
}

// Round 5
// 258.305 us; speedup vs baseline: 1.3654x; 1.0454x over previous
//
#include <hip/hip_runtime.h>
#include <hip/hip_bf16.h>

#define G     32
#define NPG   512
#define EPG   8192
#define GN    16384        // G*NPG
#define ETOT  (G*EPG)      // 262144
#define CIN   64
#define H     128
#define NB    4
#define S     4096         // T*NPG
#define HEADS 4
#define HD    32
#define QKV   384

typedef __attribute__((ext_vector_type(8))) short short8;
typedef __attribute__((ext_vector_type(4))) float floatx4;

__device__ __forceinline__ float bf16_to_f32(unsigned short u) {
    unsigned int x = ((unsigned int)u) << 16;
    return __uint_as_float(x);
}
__device__ __forceinline__ unsigned short f32_to_bf16(float f) {
    __hip_bfloat16 h = (__hip_bfloat16)f;
    return *(unsigned short*)&h;
}
__device__ __forceinline__ float ldf(const void* p, long i, int f32) {
    return f32 ? ((const float*)p)[i] : bf16_to_f32(((const unsigned short*)p)[i]);
}

// ---------- runtime dtype detection ----------
__global__ void detect_kernel(const unsigned short* __restrict__ xraw,
                              const int* __restrict__ eiraw, int* __restrict__ flags) {
    __shared__ float smax[256];
    __shared__ int   sor[256];
    int t = threadIdx.x;
    float m = 0.f;
    for (int i = t; i < 4096; i += 256)
        m = fmaxf(m, fabsf(bf16_to_f32(xraw[i])));
    int orv = 0;
    for (int i = t; i < 2048; i += 256)
        orv |= eiraw[2 * i + 1];
    smax[t] = m; sor[t] = orv;
    __syncthreads();
    for (int off = 128; off > 0; off >>= 1) {
        if (t < off) {
            smax[t] = fmaxf(smax[t], smax[t + off]);
            sor[t] |= sor[t + off];
        }
        __syncthreads();
    }
    if (t == 0) {
        flags[0] = (smax[0] > 1000.f) ? 1 : 0;
        flags[1] = (sor[0] == 0) ? 1 : 0;
    }
}

// ---------- fused conversion: everything -> bf16 (weights pre-transposed) ----------
// x is additionally scaled by dinv[node] so GCN layer 1 can aggregate BEFORE the
// matmul: (D^-1/2 A D^-1/2)(X W) = ((D^-1/2 A D^-1/2) X) W  — halves gather bytes.
#define XN   (GN*CIN)          // x:      [0,      XN)
#define E1   (XN + H*CIN)      // W1T
#define E2   (E1 + H*H)        // W2T
#define E3   (E2 + QKV*H)      // Wqkv
#define E4   (E3 + H*H)        // Wo
#define E5   (E4 + H)          // b1
#define E6   (E5 + H)          // b2
#define E7   (E6 + QKV)        // bqkv
#define CTOT (E7 + H)          // bo
__global__ void conv_all_kernel(const void* x_raw, const void* W1_raw, const void* b1_raw,
                                const void* W2_raw, const void* b2_raw, const void* Wq_raw,
                                const void* bq_raw, const void* Wo_raw, const void* bo_raw,
                                unsigned short* __restrict__ xb,
                                unsigned short* __restrict__ W1T,
                                unsigned short* __restrict__ W2T,
                                unsigned short* __restrict__ Wqb,
                                unsigned short* __restrict__ Wob,
                                float* __restrict__ b1f, float* __restrict__ b2f,
                                float* __restrict__ bqf, float* __restrict__ bof,
                                const float* __restrict__ dinv,
                                const int* __restrict__ flags) {
    int i = blockIdx.x * blockDim.x + threadIdx.x;
    if (i >= CTOT) return;
    int f32 = flags[0];
    if (i < XN) {              // x scaled by dinv of its node (CIN=64 -> node = i>>6)
        xb[i] = f32_to_bf16(ldf(x_raw, i, f32) * dinv[i >> 6]);
    } else if (i < E1) {       // W1T[c][r] = W1[r][c], [H out][CIN in]
        int j = i - XN, c = j / CIN, r = j - c * CIN;
        W1T[j] = f32_to_bf16(ldf(W1_raw, (long)r * H + c, f32));
    } else if (i < E2) {       // W2T[c][r] = W2[r][c]
        int j = i - E1, c = j >> 7, r = j & 127;
        W2T[j] = f32_to_bf16(ldf(W2_raw, (long)r * H + c, f32));
    } else if (i < E3) {       // in_proj_w already [out][in]
        int j = i - E2;
        Wqb[j] = f32_to_bf16(ldf(Wq_raw, j, f32));
    } else if (i < E4) {
        int j = i - E3;
        Wob[j] = f32_to_bf16(ldf(Wo_raw, j, f32));
    } else if (i < E5) { b1f[i - E4] = ldf(b1_raw, i - E4, f32); }
    else if (i < E6) { b2f[i - E5] = ldf(b2_raw, i - E5, f32); }
    else if (i < E7) { bqf[i - E6] = ldf(bq_raw, i - E6, f32); }
    else             { bof[i - E7] = ldf(bo_raw, i - E7, f32); }
}

// ---------- edges + degree count (fused) ----------
__global__ void edges_count_kernel(const int* __restrict__ ei, int* __restrict__ srcA,
                                   int* __restrict__ dstA, int* __restrict__ cnt,
                                   const int* __restrict__ flags) {
    int t = blockIdx.x * blockDim.x + threadIdx.x;
    if (t >= ETOT) return;
    int g = t >> 13, e = t & (EPG - 1);
    int sh = flags[1];
    long long si = ((long long)(g * 2 + 0) * EPG + e) << sh;
    long long di = ((long long)(g * 2 + 1) * EPG + e) << sh;
    int s = g * NPG + ei[si];
    int d = g * NPG + ei[di];
    srcA[t] = s;
    dstA[t] = d;
    atomicAdd(&cnt[d], 1);
}

__global__ void scan_kernel(const int* __restrict__ cnt, int* __restrict__ row_start,
                            int* __restrict__ fill_pos, float* __restrict__ dinv) {
    __shared__ int tmp[NPG];
    int g = blockIdx.x, t = threadIdx.x;
    int c = cnt[g * NPG + t];
    tmp[t] = c;
    __syncthreads();
    for (int off = 1; off < NPG; off <<= 1) {
        int v = (t >= off) ? tmp[t - off] : 0;
        __syncthreads();
        tmp[t] += v;
        __syncthreads();
    }
    int excl = tmp[t] - c;
    int rs = g * EPG + excl;
    row_start[g * NPG + t] = rs;
    fill_pos[g * NPG + t]  = rs;
    dinv[g * NPG + t] = 1.0f / sqrtf((float)c + 1.0f);
}

__global__ void fill_kernel(const int* __restrict__ srcA, const int* __restrict__ dstA,
                            int* __restrict__ fill_pos, int* __restrict__ csr_src) {
    int t = blockIdx.x * blockDim.x + threadIdx.x;
    if (t >= ETOT) return;
    int pos = atomicAdd(&fill_pos[dstA[t]], 1);
    csr_src[pos] = srcA[t];
}

// ---------- layer-1 aggregation on raw (scaled) x, CIN=64, 1 wave/block ----------
// xb already holds x_j * dinv_j; z_i = dinv_i * (sum_neigh xb_s + xb_i)
__global__ void agg64_kernel(const unsigned short* __restrict__ xb,
                             const int* __restrict__ row_start, const int* __restrict__ cnt,
                             const int* __restrict__ csr_src, const float* __restrict__ dinv,
                             unsigned short* __restrict__ z) {
    int i = blockIdx.x;
    int c = threadIdx.x;                    // 0..63
    float acc = bf16_to_f32(xb[(size_t)i * CIN + c]);   // self term
    int rs = row_start[i], n = cnt[i];
    int p = 0;
    for (; p + 4 <= n; p += 4) {
        int s0 = csr_src[rs + p + 0];
        int s1 = csr_src[rs + p + 1];
        int s2 = csr_src[rs + p + 2];
        int s3 = csr_src[rs + p + 3];
        float a0 = bf16_to_f32(xb[(size_t)s0 * CIN + c]);
        float a1 = bf16_to_f32(xb[(size_t)s1 * CIN + c]);
        float a2 = bf16_to_f32(xb[(size_t)s2 * CIN + c]);
        float a3 = bf16_to_f32(xb[(size_t)s3 * CIN + c]);
        acc += (a0 + a1) + (a2 + a3);
    }
    for (; p < n; p++)
        acc += bf16_to_f32(xb[(size_t)csr_src[rs + p] * CIN + c]);
    z[(size_t)i * CIN + c] = f32_to_bf16(acc * dinv[i]);
}

// ---------- plain MFMA GEMM + bias: Y[row][col] = A[row][:].B[col][:] + bias[col]
template<int KD>
__global__ __launch_bounds__(256) void mm_bias_kernel(const unsigned short* __restrict__ A,
        const unsigned short* __restrict__ B, const float* __restrict__ bias,
        unsigned short* __restrict__ Y) {
    int tid = threadIdx.x, wave = tid >> 6, lane = tid & 63, m = lane & 15, quad = lane >> 4;
    int row0 = blockIdx.x * 64 + wave * 16;
    floatx4 acc[8] = {};
    for (int kc = 0; kc < KD; kc += 32) {
        short8 af = *(const short8*)&A[(size_t)(row0 + m) * KD + kc + quad * 8];
#pragma unroll
        for (int t = 0; t < 8; t++) {
            short8 bf = *(const short8*)&B[(size_t)(t * 16 + m) * KD + kc + quad * 8];
            acc[t] = __builtin_amdgcn_mfma_f32_16x16x32_bf16(af, bf, acc[t], 0, 0, 0);
        }
    }
    int rbase = row0 + quad * 4;
#pragma unroll
    for (int t = 0; t < 8; t++) {
        int col = t * 16 + m;
        float bj = bias[col];
#pragma unroll
        for (int r = 0; r < 4; r++)
            Y[(size_t)(rbase + r) * H + col] = f32_to_bf16(acc[t][r] + bj);
    }
}

// ---------- MFMA GEMM: Y[row][col] = (A[row][:] . B[col][:]) * dinv[row]  (bf16 out)
template<int KD>
__global__ __launch_bounds__(256) void mm_gcn_kernel(const unsigned short* __restrict__ A,
        const unsigned short* __restrict__ B, const float* __restrict__ dinv,
        unsigned short* __restrict__ Y) {
    int tid = threadIdx.x, wave = tid >> 6, lane = tid & 63, m = lane & 15, quad = lane >> 4;
    int row0 = blockIdx.x * 64 + wave * 16;
    floatx4 acc[8] = {};
    for (int kc = 0; kc < KD; kc += 32) {
        short8 af = *(const short8*)&A[(size_t)(row0 + m) * KD + kc + quad * 8];
#pragma unroll
        for (int t = 0; t < 8; t++) {
            short8 bf = *(const short8*)&B[(size_t)(t * 16 + m) * KD + kc + quad * 8];
            acc[t] = __builtin_amdgcn_mfma_f32_16x16x32_bf16(af, bf, acc[t], 0, 0, 0);
        }
    }
    int rbase = row0 + quad * 4;
    float4 dv4 = *(const float4*)&dinv[rbase];
    float dv[4] = {dv4.x, dv4.y, dv4.z, dv4.w};
#pragma unroll
    for (int t = 0; t < 8; t++) {
        int col = t * 16 + m;
#pragma unroll
        for (int r = 0; r < 4; r++)
            Y[(size_t)(rbase + r) * H + col] = f32_to_bf16(acc[t][r] * dv[r]);
    }
}

// ---------- GCN aggregation (bf16 in/out, f32 accum), gather unrolled x4 ----------
__global__ void agg_kernel(const unsigned short* __restrict__ y,
                           const int* __restrict__ row_start, const int* __restrict__ cnt,
                           const int* __restrict__ csr_src, const float* __restrict__ dinv,
                           const float* __restrict__ bias, unsigned short* __restrict__ hout) {
    int i = blockIdx.x;
    int c = threadIdx.x;
    float acc = bf16_to_f32(y[(size_t)i * H + c]);   // self-loop
    int rs = row_start[i], n = cnt[i];
    int p = 0;
    for (; p + 4 <= n; p += 4) {
        int s0 = csr_src[rs + p + 0];
        int s1 = csr_src[rs + p + 1];
        int s2 = csr_src[rs + p + 2];
        int s3 = csr_src[rs + p + 3];
        float a0 = bf16_to_f32(y[(size_t)s0 * H + c]);
        float a1 = bf16_to_f32(y[(size_t)s1 * H + c]);
        float a2 = bf16_to_f32(y[(size_t)s2 * H + c]);
        float a3 = bf16_to_f32(y[(size_t)s3 * H + c]);
        acc += (a0 + a1) + (a2 + a3);
    }
    for (; p < n; p++)
        acc += bf16_to_f32(y[(size_t)csr_src[rs + p] * H + c]);
    hout[(size_t)i * H + c] = f32_to_bf16(acc * dinv[i] + bias[c]);
}

// ---------- QKV GEMM (N=384) with blocked epilogue ----------
// Q pre-scale folds log2(e) so attention can use raw v_exp_f32 (2^x).
__global__ __launch_bounds__(256) void mmqkv_kernel(const unsigned short* __restrict__ A,
        const unsigned short* __restrict__ B, const float* __restrict__ bias,
        unsigned short* __restrict__ Qx, unsigned short* __restrict__ Kx,
        unsigned short* __restrict__ Vtx) {
    int tid = threadIdx.x, wave = tid >> 6, lane = tid & 63, m = lane & 15, quad = lane >> 4;
    int row0 = blockIdx.x * 64 + wave * 16;
    floatx4 acc[24] = {};
    for (int kc = 0; kc < H; kc += 32) {
        short8 af = *(const short8*)&A[(size_t)(row0 + m) * H + kc + quad * 8];
#pragma unroll
        for (int t = 0; t < 24; t++) {
            short8 bf = *(const short8*)&B[(size_t)(t * 16 + m) * H + kc + quad * 8];
            acc[t] = __builtin_amdgcn_mfma_f32_16x16x32_bf16(af, bf, acc[t], 0, 0, 0);
        }
    }
    int rbase = row0 + quad * 4;                    // rows rbase..rbase+3, same batch
    int b = rbase >> 12, s0 = rbase & (S - 1);
#pragma unroll
    for (int t = 0; t < 24; t++) {
        int j = t * 16 + m;                         // 0..383
        float bj = bias[j];
        int jj = j & 127, head = jj >> 5, hd = jj & 31;
        int bh = b * HEADS + head;
        if (t < 8) {                                // Q (pre-scaled by log2e/sqrt(hd))
#pragma unroll
            for (int r = 0; r < 4; r++)
                Qx[((size_t)bh * S + s0 + r) * HD + hd] =
                    f32_to_bf16((acc[t][r] + bj) *
                                (0.17677669529663687f * 1.4426950408889634f));
        } else if (t < 16) {                        // K
#pragma unroll
            for (int r = 0; r < 4; r++)
                Kx[((size_t)bh * S + s0 + r) * HD + hd] = f32_to_bf16(acc[t][r] + bj);
        } else {                                    // V transposed
#pragma unroll
            for (int r = 0; r < 4; r++)
                Vtx[((size_t)bh * HD + hd) * S + s0 + r] = f32_to_bf16(acc[t][r] + bj);
        }
    }
}

// ---------- MFMA flash attention v7: 64 q-rows/wave, zero LDS, in-register P
// transpose, l on the MFMA pipe, XCD swizzle (2 bh-streams per XCD-L2).
// grid 256 (1 block/CU, 1 wave/SIMD), block 256.
__global__ __launch_bounds__(256) void attn7_kernel(
        const unsigned short* __restrict__ Qx, const unsigned short* __restrict__ Kx,
        const unsigned short* __restrict__ Vtx, unsigned short* __restrict__ Ob) {
    int tid = threadIdx.x, wave = tid >> 6, lane = tid & 63;
    int m = lane & 15, quad = lane >> 4;

    int n = blockIdx.x;                       // 0..255, XCD ~ n%8
    int id = (n & 7) * 32 + (n >> 3);         // XCD x owns ids [32x,32x+32) -> bh {2x,2x+1}
    int tile = id & 15, bh = id >> 4;

    const unsigned short* Qb  = Qx  + (size_t)bh * S * HD;
    const unsigned short* Kb  = Kx  + (size_t)bh * S * HD;
    const unsigned short* Vtb = Vtx + (size_t)bh * HD * S;

    int q0 = tile * 256 + wave * 64;
    short8 q[4];
#pragma unroll
    for (int t = 0; t < 4; t++)
        q[t] = *(const short8*)&Qb[(size_t)(q0 + t * 16 + m) * HD + quad * 8];

    floatx4 o0[4] = {}, o1[4] = {}, l[4] = {};

    short8 ones = {16256, 16256, 16256, 16256, 16256, 16256, 16256, 16256}; // bf16 1.0
    union PW { unsigned int u[4]; short8 s8; };

    // chunk 0 K/V
    short8 kf0 = *(const short8*)&Kb[(size_t)m * HD + quad * 8];
    short8 kf1 = *(const short8*)&Kb[(size_t)(m + 16) * HD + quad * 8];
    short8 vc0 = *(const short8*)&Vtb[(size_t)m * S + quad * 8];
    short8 vc1 = *(const short8*)&Vtb[(size_t)(m + 16) * S + quad * 8];

    for (int i = 0; i < S / 32; i++) {
        floatx4 z = {};
        // swapped QK^T for all 4 q-tiles (lane(m,quad): P^T[k=quad*4+r][q=m])
        floatx4 t0[4], t1[4];
#pragma unroll
        for (int t = 0; t < 4; t++) {
            t0[t] = __builtin_amdgcn_mfma_f32_16x16x32_bf16(kf0, q[t], z, 0, 0, 0);
            t1[t] = __builtin_amdgcn_mfma_f32_16x16x32_bf16(kf1, q[t], z, 0, 0, 0);
        }
        // K prefetch for chunk i+1 (used at top of next iter, ~full iter ahead)
        int ktn = ((i + 1) * 32) & (S - 1);
        kf0 = *(const short8*)&Kb[(size_t)(ktn + m) * HD + quad * 8];
        kf1 = *(const short8*)&Kb[(size_t)(ktn + m + 16) * HD + quad * 8];

        // exp2 -> pack bf16 -> in-register transpose, per tile
        PW pw[4];
#pragma unroll
        for (int t = 0; t < 4; t++) {
            float e0 = __builtin_amdgcn_exp2f(t0[t][0]);
            float e1 = __builtin_amdgcn_exp2f(t0[t][1]);
            float e2 = __builtin_amdgcn_exp2f(t0[t][2]);
            float e3 = __builtin_amdgcn_exp2f(t0[t][3]);
            float e4 = __builtin_amdgcn_exp2f(t1[t][0]);
            float e5 = __builtin_amdgcn_exp2f(t1[t][1]);
            float e6 = __builtin_amdgcn_exp2f(t1[t][2]);
            float e7 = __builtin_amdgcn_exp2f(t1[t][3]);
            unsigned int w0, w1, w2, w3;
            asm("v_cvt_pk_bf16_f32 %0, %1, %2" : "=v"(w0) : "v"(e0), "v"(e1));
            asm("v_cvt_pk_bf16_f32 %0, %1, %2" : "=v"(w1) : "v"(e2), "v"(e3));
            asm("v_cvt_pk_bf16_f32 %0, %1, %2" : "=v"(w2) : "v"(e4), "v"(e5));
            asm("v_cvt_pk_bf16_f32 %0, %1, %2" : "=v"(w3) : "v"(e6), "v"(e7));
            asm("v_permlane32_swap_b32 %0, %1" : "+v"(w0), "+v"(w2));
            asm("v_permlane32_swap_b32 %0, %1" : "+v"(w1), "+v"(w3));
            asm("v_permlane16_swap_b32 %0, %1" : "+v"(w0), "+v"(w2));
            asm("v_permlane16_swap_b32 %0, %1" : "+v"(w1), "+v"(w3));
            pw[t].u[0] = w0; pw[t].u[1] = w1; pw[t].u[2] = w2; pw[t].u[3] = w3;
        }

        // PV + row-sum l (MFMA pipe), then V prefetch for chunk i+1
#pragma unroll
        for (int t = 0; t < 4; t++) {
            o0[t] = __builtin_amdgcn_mfma_f32_16x16x32_bf16(pw[t].s8, vc0, o0[t], 0, 0, 0);
            o1[t] = __builtin_amdgcn_mfma_f32_16x16x32_bf16(pw[t].s8, vc1, o1[t], 0, 0, 0);
            l[t]  = __builtin_amdgcn_mfma_f32_16x16x32_bf16(pw[t].s8, ones, l[t], 0, 0, 0);
        }
        vc0 = *(const short8*)&Vtb[(size_t)m * S + ktn + quad * 8];
        vc1 = *(const short8*)&Vtb[(size_t)(m + 16) * S + ktn + quad * 8];
    }

    // epilogue: l is row-aligned with O (row = quad*4+r), no shuffles
    int batch = bh >> 2, head = bh & 3;
    int col = head * HD + m;
#pragma unroll
    for (int t = 0; t < 4; t++) {
        int grow = batch * S + q0 + t * 16 + quad * 4;
#pragma unroll
        for (int r = 0; r < 4; r++) {
            float inv = 1.f / l[t][r];
            Ob[(size_t)(grow + r) * H + col]      = f32_to_bf16(o0[t][r] * inv);
            Ob[(size_t)(grow + r) * H + col + 16] = f32_to_bf16(o1[t][r] * inv);
        }
    }
}

// ---------- output projection GEMM (N=128) + bias, dual-dtype store ----------
__global__ __launch_bounds__(256) void mmout_kernel(const unsigned short* __restrict__ A,
        const unsigned short* __restrict__ B, const float* __restrict__ bias,
        void* __restrict__ out, const int* __restrict__ flags) {
    int tid = threadIdx.x, wave = tid >> 6, lane = tid & 63, m = lane & 15, quad = lane >> 4;
    int row0 = blockIdx.x * 64 + wave * 16;
    floatx4 acc[8] = {};
    for (int kc = 0; kc < H; kc += 32) {
        short8 af = *(const short8*)&A[(size_t)(row0 + m) * H + kc + quad * 8];
#pragma unroll
        for (int t = 0; t < 8; t++) {
            short8 bf = *(const short8*)&B[(size_t)(t * 16 + m) * H + kc + quad * 8];
            acc[t] = __builtin_amdgcn_mfma_f32_16x16x32_bf16(af, bf, acc[t], 0, 0, 0);
        }
    }
    int rbase = row0 + quad * 4;
    int f32o = flags[0];
#pragma unroll
    for (int t = 0; t < 8; t++) {
        int col = t * 16 + m;
        float bj = bias[col];
#pragma unroll
        for (int r = 0; r < 4; r++) {
            float v = acc[t][r] + bj;
            if (f32o) ((float*)out)[(size_t)(rbase + r) * H + col] = v;
            else ((unsigned short*)out)[(size_t)(rbase + r) * H + col] = f32_to_bf16(v);
        }
    }
}

extern "C" void kernel_launch(void* const* d_in, const int* in_sizes, int n_in,
                              void* d_out, int out_size, void* d_ws, size_t ws_size,
                              hipStream_t stream) {
    const void* x_raw    = d_in[0];
    const int*  ei_raw   = (const int*)d_in[1];
    const void* W1_raw   = d_in[2];
    const void* b1_raw   = d_in[3];
    const void* W2_raw   = d_in[4];
    const void* b2_raw   = d_in[5];
    const void* Wq_raw   = d_in[6];
    const void* bq_raw   = d_in[7];
    const void* Wo_raw   = d_in[8];
    const void* bo_raw   = d_in[9];

    char* ws = (char*)d_ws;
    size_t o = 0;
    auto alloc = [&](size_t bytes) { void* p = ws + o; o += (bytes + 1023) & ~1023ull; return p; };

    int*   flags     = (int*)  alloc(1024);
    int*   cnt       = (int*)  alloc((size_t)GN * 4);
    int*   row_start = (int*)  alloc((size_t)GN * 4);
    int*   fill_pos  = (int*)  alloc((size_t)GN * 4);
    float* dinv      = (float*)alloc((size_t)GN * 4);
    int*   srcA      = (int*)  alloc((size_t)ETOT * 4);
    int*   dstA      = (int*)  alloc((size_t)ETOT * 4);
    int*   csr_src   = (int*)  alloc((size_t)ETOT * 4);
    unsigned short* xb   = (unsigned short*)alloc((size_t)GN * CIN * 2);
    unsigned short* zb   = (unsigned short*)alloc((size_t)GN * CIN * 2);
    unsigned short* W1T  = (unsigned short*)alloc((size_t)H * CIN * 2);
    unsigned short* W2T  = (unsigned short*)alloc((size_t)H * H * 2);
    unsigned short* Wqb  = (unsigned short*)alloc((size_t)QKV * H * 2);
    unsigned short* Wob  = (unsigned short*)alloc((size_t)H * H * 2);
    float* b1f = (float*)alloc(H * 4);
    float* b2f = (float*)alloc(H * 4);
    float* bqf = (float*)alloc(QKV * 4);
    float* bof = (float*)alloc(H * 4);
    unsigned short* y_bf = (unsigned short*)alloc((size_t)GN * H * 2);
    unsigned short* h_bf = (unsigned short*)alloc((size_t)GN * H * 2);
    unsigned short* Qx   = (unsigned short*)alloc((size_t)16 * S * HD * 2);
    unsigned short* Kx   = (unsigned short*)alloc((size_t)16 * S * HD * 2);
    unsigned short* Vtx  = (unsigned short*)alloc((size_t)16 * S * HD * 2);
    unsigned short* Obf  = y_bf;   // y dead after second agg

    detect_kernel<<<1, 256, 0, stream>>>((const unsigned short*)x_raw, ei_raw, flags);

    hipMemsetAsync(cnt, 0, (size_t)GN * 4, stream);
    edges_count_kernel<<<ETOT / 256, 256, 0, stream>>>(ei_raw, srcA, dstA, cnt, flags);
    scan_kernel<<<G, NPG, 0, stream>>>(cnt, row_start, fill_pos, dinv);

    // conversion needs dinv (x pre-scaled by dinv for the reassociated layer 1)
    conv_all_kernel<<<(CTOT + 255) / 256, 256, 0, stream>>>(
        x_raw, W1_raw, b1_raw, W2_raw, b2_raw, Wq_raw, bq_raw, Wo_raw, bo_raw,
        xb, W1T, W2T, Wqb, Wob, b1f, b2f, bqf, bof, dinv, flags);

    fill_kernel<<<ETOT / 256, 256, 0, stream>>>(srcA, dstA, fill_pos, csr_src);

    // GCN layer 1 (aggregate on 64ch, then matmul+bias)
    agg64_kernel<<<GN, CIN, 0, stream>>>(xb, row_start, cnt, csr_src, dinv, zb);
    mm_bias_kernel<CIN><<<GN / 64, 256, 0, stream>>>(zb, W1T, b1f, h_bf);
    // GCN layer 2 (matmul*dinv, then aggregate+bias)
    mm_gcn_kernel<H><<<GN / 64, 256, 0, stream>>>(h_bf, W2T, dinv, y_bf);
    agg_kernel<<<GN, H, 0, stream>>>(y_bf, row_start, cnt, csr_src, dinv, b2f, h_bf);

    // attention
    mmqkv_kernel<<<GN / 64, 256, 0, stream>>>(h_bf, Wqb, bqf, Qx, Kx, Vtx);
    attn7_kernel<<<dim3(256), 256, 0, stream>>>(Qx, Kx, Vtx, Obf);
    mmout_kernel<<<GN / 64, 256, 0, stream>>>(Obf, Wob, bof, d_out, flags);
}

// Round 6
// 249.892 us; speedup vs baseline: 1.4114x; 1.0337x over previous
//
#include <hip/hip_runtime.h>
#include <hip/hip_bf16.h>

#define G     32
#define NPG   512
#define EPG   8192
#define GN    16384        // G*NPG
#define ETOT  (G*EPG)      // 262144
#define CIN   64
#define H     128
#define NB    4
#define S     4096         // T*NPG
#define HEADS 4
#define HD    32
#define QKV   384

typedef __attribute__((ext_vector_type(8))) short short8;
typedef __attribute__((ext_vector_type(4))) float floatx4;

__device__ __forceinline__ float bf16_to_f32(unsigned short u) {
    unsigned int x = ((unsigned int)u) << 16;
    return __uint_as_float(x);
}
__device__ __forceinline__ unsigned short f32_to_bf16(float f) {
    __hip_bfloat16 h = (__hip_bfloat16)f;
    return *(unsigned short*)&h;
}
__device__ __forceinline__ float ldf(const void* p, long i, int f32) {
    return f32 ? ((const float*)p)[i] : bf16_to_f32(((const unsigned short*)p)[i]);
}

// ---------- runtime dtype detection ----------
__global__ void detect_kernel(const unsigned short* __restrict__ xraw,
                              const int* __restrict__ eiraw, int* __restrict__ flags) {
    __shared__ float smax[256];
    __shared__ int   sor[256];
    int t = threadIdx.x;
    float m = 0.f;
    for (int i = t; i < 4096; i += 256)
        m = fmaxf(m, fabsf(bf16_to_f32(xraw[i])));
    int orv = 0;
    for (int i = t; i < 2048; i += 256)
        orv |= eiraw[2 * i + 1];
    smax[t] = m; sor[t] = orv;
    __syncthreads();
    for (int off = 128; off > 0; off >>= 1) {
        if (t < off) {
            smax[t] = fmaxf(smax[t], smax[t + off]);
            sor[t] |= sor[t + off];
        }
        __syncthreads();
    }
    if (t == 0) {
        flags[0] = (smax[0] > 1000.f) ? 1 : 0;
        flags[1] = (sor[0] == 0) ? 1 : 0;
    }
}

// ---------- CSR build: count + scan + dinv + fill, one block per graph ----------
// LDS atomics replace 2x 262k global atomics; srcA/dstA round-trip eliminated.
__global__ __launch_bounds__(NPG) void csr_kernel(const int* __restrict__ ei,
        const int* __restrict__ flags, int* __restrict__ cnt_g,
        int* __restrict__ row_start_g, float* __restrict__ dinv_g,
        int* __restrict__ csr_src) {
    __shared__ int cs[NPG], ctmp[NPG], fpos[NPG];
    int g = blockIdx.x, t = threadIdx.x;
    int sh = flags[1];
    cs[t] = 0;
    __syncthreads();
    const size_t sbase = ((size_t)(g * 2 + 0) * EPG) << sh;
    const size_t dbase = ((size_t)(g * 2 + 1) * EPG) << sh;
    for (int e = t; e < EPG; e += NPG)
        atomicAdd(&cs[ei[dbase + ((size_t)e << sh)]], 1);
    __syncthreads();
    int c = cs[t];
    ctmp[t] = c;
    __syncthreads();
    for (int off = 1; off < NPG; off <<= 1) {
        int v = (t >= off) ? ctmp[t - off] : 0;
        __syncthreads();
        ctmp[t] += v;
        __syncthreads();
    }
    int rs = g * EPG + ctmp[t] - c;            // exclusive prefix
    fpos[t] = rs;
    cnt_g[g * NPG + t] = c;
    row_start_g[g * NPG + t] = rs;
    dinv_g[g * NPG + t] = 1.0f / sqrtf((float)c + 1.0f);
    __syncthreads();
    for (int e = t; e < EPG; e += NPG) {
        int s = ei[sbase + ((size_t)e << sh)];
        int d = ei[dbase + ((size_t)e << sh)];
        int pos = atomicAdd(&fpos[d], 1);
        csr_src[pos] = g * NPG + s;
    }
}

// ---------- fused conversion: everything -> bf16 (weights pre-transposed) ----------
// x additionally scaled by dinv[node] (reassociated GCN layer 1).
#define XN   (GN*CIN)          // x:      [0,      XN)
#define E1   (XN + H*CIN)      // W1T
#define E2   (E1 + H*H)        // W2T
#define E3   (E2 + QKV*H)      // Wqkv
#define E4   (E3 + H*H)        // Wo
#define E5   (E4 + H)          // b1
#define E6   (E5 + H)          // b2
#define E7   (E6 + QKV)        // bqkv
#define CTOT (E7 + H)          // bo
__global__ void conv_all_kernel(const void* x_raw, const void* W1_raw, const void* b1_raw,
                                const void* W2_raw, const void* b2_raw, const void* Wq_raw,
                                const void* bq_raw, const void* Wo_raw, const void* bo_raw,
                                unsigned short* __restrict__ xb,
                                unsigned short* __restrict__ W1T,
                                unsigned short* __restrict__ W2T,
                                unsigned short* __restrict__ Wqb,
                                unsigned short* __restrict__ Wob,
                                float* __restrict__ b1f, float* __restrict__ b2f,
                                float* __restrict__ bqf, float* __restrict__ bof,
                                const float* __restrict__ dinv,
                                const int* __restrict__ flags) {
    int i = blockIdx.x * blockDim.x + threadIdx.x;
    if (i >= CTOT) return;
    int f32 = flags[0];
    if (i < XN) {              // x scaled by dinv of its node (CIN=64 -> node = i>>6)
        xb[i] = f32_to_bf16(ldf(x_raw, i, f32) * dinv[i >> 6]);
    } else if (i < E1) {       // W1T[c][r] = W1[r][c], [H out][CIN in]
        int j = i - XN, c = j / CIN, r = j - c * CIN;
        W1T[j] = f32_to_bf16(ldf(W1_raw, (long)r * H + c, f32));
    } else if (i < E2) {       // W2T[c][r] = W2[r][c]
        int j = i - E1, c = j >> 7, r = j & 127;
        W2T[j] = f32_to_bf16(ldf(W2_raw, (long)r * H + c, f32));
    } else if (i < E3) {       // in_proj_w already [out][in]
        int j = i - E2;
        Wqb[j] = f32_to_bf16(ldf(Wq_raw, j, f32));
    } else if (i < E4) {
        int j = i - E3;
        Wob[j] = f32_to_bf16(ldf(Wo_raw, j, f32));
    } else if (i < E5) { b1f[i - E4] = ldf(b1_raw, i - E4, f32); }
    else if (i < E6) { b2f[i - E5] = ldf(b2_raw, i - E5, f32); }
    else if (i < E7) { bqf[i - E6] = ldf(bq_raw, i - E6, f32); }
    else             { bof[i - E7] = ldf(bo_raw, i - E7, f32); }
}

// ---------- layer-1 aggregation on raw (scaled) x, CIN=64, 1 wave/block ----------
// xb already holds x_j * dinv_j; z_i = dinv_i * (sum_neigh xb_s + xb_i)
__global__ void agg64_kernel(const unsigned short* __restrict__ xb,
                             const int* __restrict__ row_start, const int* __restrict__ cnt,
                             const int* __restrict__ csr_src, const float* __restrict__ dinv,
                             unsigned short* __restrict__ z) {
    int i = blockIdx.x;
    int c = threadIdx.x;                    // 0..63
    float acc = bf16_to_f32(xb[(size_t)i * CIN + c]);   // self term
    int rs = row_start[i], n = cnt[i];
    int p = 0;
    for (; p + 4 <= n; p += 4) {
        int s0 = csr_src[rs + p + 0];
        int s1 = csr_src[rs + p + 1];
        int s2 = csr_src[rs + p + 2];
        int s3 = csr_src[rs + p + 3];
        float a0 = bf16_to_f32(xb[(size_t)s0 * CIN + c]);
        float a1 = bf16_to_f32(xb[(size_t)s1 * CIN + c]);
        float a2 = bf16_to_f32(xb[(size_t)s2 * CIN + c]);
        float a3 = bf16_to_f32(xb[(size_t)s3 * CIN + c]);
        acc += (a0 + a1) + (a2 + a3);
    }
    for (; p < n; p++)
        acc += bf16_to_f32(xb[(size_t)csr_src[rs + p] * CIN + c]);
    z[(size_t)i * CIN + c] = f32_to_bf16(acc * dinv[i]);
}

// ---------- fused GCN GEMMs: h = z*W1+b1 (K=64) -> LDS -> y = (h*W2)*dinv (K=128)
// h tile (64x128 bf16) lives only in LDS (padded to 136 for conflict-free b128
// reads, 272B row = 16B-aligned).  Each wave reads only its own 16 rows -> no
// barrier, just lgkmcnt.  Removes 4MB write + 4MB read + 1 dispatch.
#define HPAD 136
__global__ __launch_bounds__(256) void gcn12_kernel(
        const unsigned short* __restrict__ Z, const unsigned short* __restrict__ W1T,
        const float* __restrict__ b1, const unsigned short* __restrict__ W2T,
        const float* __restrict__ dinv, unsigned short* __restrict__ Y) {
    __shared__ unsigned short hl[64][HPAD];
    int tid = threadIdx.x, wave = tid >> 6, lane = tid & 63, m = lane & 15, quad = lane >> 4;
    int row0 = blockIdx.x * 64 + wave * 16;
    int lrow0 = wave * 16;
    floatx4 acc[8] = {};
    for (int kc = 0; kc < CIN; kc += 32) {
        short8 af = *(const short8*)&Z[(size_t)(row0 + m) * CIN + kc + quad * 8];
#pragma unroll
        for (int t = 0; t < 8; t++) {
            short8 bf = *(const short8*)&W1T[(size_t)(t * 16 + m) * CIN + kc + quad * 8];
            acc[t] = __builtin_amdgcn_mfma_f32_16x16x32_bf16(af, bf, acc[t], 0, 0, 0);
        }
    }
#pragma unroll
    for (int t = 0; t < 8; t++) {
        int col = t * 16 + m;
        float bj = b1[col];
#pragma unroll
        for (int r = 0; r < 4; r++)
            hl[lrow0 + quad * 4 + r][col] = f32_to_bf16(acc[t][r] + bj);
    }
    asm volatile("s_waitcnt lgkmcnt(0)" ::: "memory");
    floatx4 acc2[8] = {};
    for (int kc = 0; kc < H; kc += 32) {
        short8 af = *(const short8*)&hl[lrow0 + m][kc + quad * 8];
#pragma unroll
        for (int t = 0; t < 8; t++) {
            short8 bf = *(const short8*)&W2T[(size_t)(t * 16 + m) * H + kc + quad * 8];
            acc2[t] = __builtin_amdgcn_mfma_f32_16x16x32_bf16(af, bf, acc2[t], 0, 0, 0);
        }
    }
    int rbase = row0 + quad * 4;
    float4 dv4 = *(const float4*)&dinv[rbase];
    float dv[4] = {dv4.x, dv4.y, dv4.z, dv4.w};
#pragma unroll
    for (int t = 0; t < 8; t++) {
        int col = t * 16 + m;
#pragma unroll
        for (int r = 0; r < 4; r++)
            Y[(size_t)(rbase + r) * H + col] = f32_to_bf16(acc2[t][r] * dv[r]);
    }
}

// ---------- GCN aggregation (bf16 in/out, f32 accum), gather unrolled x4 ----------
__global__ void agg_kernel(const unsigned short* __restrict__ y,
                           const int* __restrict__ row_start, const int* __restrict__ cnt,
                           const int* __restrict__ csr_src, const float* __restrict__ dinv,
                           const float* __restrict__ bias, unsigned short* __restrict__ hout) {
    int i = blockIdx.x;
    int c = threadIdx.x;
    float acc = bf16_to_f32(y[(size_t)i * H + c]);   // self-loop
    int rs = row_start[i], n = cnt[i];
    int p = 0;
    for (; p + 4 <= n; p += 4) {
        int s0 = csr_src[rs + p + 0];
        int s1 = csr_src[rs + p + 1];
        int s2 = csr_src[rs + p + 2];
        int s3 = csr_src[rs + p + 3];
        float a0 = bf16_to_f32(y[(size_t)s0 * H + c]);
        float a1 = bf16_to_f32(y[(size_t)s1 * H + c]);
        float a2 = bf16_to_f32(y[(size_t)s2 * H + c]);
        float a3 = bf16_to_f32(y[(size_t)s3 * H + c]);
        acc += (a0 + a1) + (a2 + a3);
    }
    for (; p < n; p++)
        acc += bf16_to_f32(y[(size_t)csr_src[rs + p] * H + c]);
    hout[(size_t)i * H + c] = f32_to_bf16(acc * dinv[i] + bias[c]);
}

// ---------- QKV GEMM (N=384) with blocked epilogue ----------
// Q pre-scale folds log2(e).  V-tiles are transposed through a tiny LDS buffer
// so Vtx stores become 8B/lane coalescing into 32B runs (16x fewer transactions
// than the old 2B scatter).
__global__ __launch_bounds__(256) void mmqkv_kernel(const unsigned short* __restrict__ A,
        const unsigned short* __restrict__ B, const float* __restrict__ bias,
        unsigned short* __restrict__ Qx, unsigned short* __restrict__ Kx,
        unsigned short* __restrict__ Vtx) {
    __shared__ unsigned short vbuf[4][2][16][20];   // [wave][parity][hd][s(+pad)]
    int tid = threadIdx.x, wave = tid >> 6, lane = tid & 63, m = lane & 15, quad = lane >> 4;
    int row0 = blockIdx.x * 64 + wave * 16;
    floatx4 acc[24] = {};
    for (int kc = 0; kc < H; kc += 32) {
        short8 af = *(const short8*)&A[(size_t)(row0 + m) * H + kc + quad * 8];
#pragma unroll
        for (int t = 0; t < 24; t++) {
            short8 bf = *(const short8*)&B[(size_t)(t * 16 + m) * H + kc + quad * 8];
            acc[t] = __builtin_amdgcn_mfma_f32_16x16x32_bf16(af, bf, acc[t], 0, 0, 0);
        }
    }
    int rbase = row0 + quad * 4;                    // rows rbase..rbase+3, same batch
    int b = rbase >> 12, s0 = rbase & (S - 1);
    int s0t = row0 & (S - 1);                       // wave-tile base s (16 rows)
    int hdl = lane >> 2, sg = lane & 3;             // transposed-read mapping
#pragma unroll
    for (int t = 0; t < 24; t++) {
        int j = t * 16 + m;                         // 0..383
        float bj = bias[j];
        if (t < 8) {                                // Q (pre-scaled by log2e/sqrt(hd))
            int head = j >> 5, hd = j & 31;
            int bh = b * HEADS + head;
#pragma unroll
            for (int r = 0; r < 4; r++)
                Qx[((size_t)bh * S + s0 + r) * HD + hd] =
                    f32_to_bf16((acc[t][r] + bj) *
                                (0.17677669529663687f * 1.4426950408889634f));
        } else if (t < 16) {                        // K
            int jj = j & 127, head = jj >> 5, hd = jj & 31;
            int bh = b * HEADS + head;
#pragma unroll
            for (int r = 0; r < 4; r++)
                Kx[((size_t)bh * S + s0 + r) * HD + hd] = f32_to_bf16(acc[t][r] + bj);
        } else {                                    // V transposed via LDS
            int t2 = t - 16;                        // 0..7
            int head = t2 >> 1, hdb = (t2 & 1) * 16;
            int bh = b * HEADS + head;
            float v0 = acc[t][0] + bj, v1 = acc[t][1] + bj;
            float v2 = acc[t][2] + bj, v3 = acc[t][3] + bj;
            unsigned int d0, d1;
            asm("v_cvt_pk_bf16_f32 %0, %1, %2" : "=v"(d0) : "v"(v0), "v"(v1));
            asm("v_cvt_pk_bf16_f32 %0, %1, %2" : "=v"(d1) : "v"(v2), "v"(v3));
            uint2 wv; wv.x = d0; wv.y = d1;
            // write: row hd_local=m, cols s_local = quad*4..+3
            *(uint2*)&vbuf[wave][t2 & 1][m][quad * 4] = wv;
            asm volatile("s_waitcnt lgkmcnt(0)" ::: "memory");
            uint2 rv = *(const uint2*)&vbuf[wave][t2 & 1][hdl][sg * 4];
            *(uint2*)&Vtx[((size_t)bh * HD + hdb + hdl) * S + s0t + sg * 4] = rv;
        }
    }
}

// ---------- MFMA flash attention v7: 64 q-rows/wave, zero LDS, in-register P
// transpose, l on the MFMA pipe, XCD swizzle (2 bh-streams per XCD-L2).
// grid 256 (1 block/CU, 1 wave/SIMD), block 256.
__global__ __launch_bounds__(256) void attn7_kernel(
        const unsigned short* __restrict__ Qx, const unsigned short* __restrict__ Kx,
        const unsigned short* __restrict__ Vtx, unsigned short* __restrict__ Ob) {
    int tid = threadIdx.x, wave = tid >> 6, lane = tid & 63;
    int m = lane & 15, quad = lane >> 4;

    int n = blockIdx.x;                       // 0..255, XCD ~ n%8
    int id = (n & 7) * 32 + (n >> 3);         // XCD x owns ids [32x,32x+32) -> bh {2x,2x+1}
    int tile = id & 15, bh = id >> 4;

    const unsigned short* Qb  = Qx  + (size_t)bh * S * HD;
    const unsigned short* Kb  = Kx  + (size_t)bh * S * HD;
    const unsigned short* Vtb = Vtx + (size_t)bh * HD * S;

    int q0 = tile * 256 + wave * 64;
    short8 q[4];
#pragma unroll
    for (int t = 0; t < 4; t++)
        q[t] = *(const short8*)&Qb[(size_t)(q0 + t * 16 + m) * HD + quad * 8];

    floatx4 o0[4] = {}, o1[4] = {}, l[4] = {};

    short8 ones = {16256, 16256, 16256, 16256, 16256, 16256, 16256, 16256}; // bf16 1.0
    union PW { unsigned int u[4]; short8 s8; };

    // chunk 0 K/V
    short8 kf0 = *(const short8*)&Kb[(size_t)m * HD + quad * 8];
    short8 kf1 = *(const short8*)&Kb[(size_t)(m + 16) * HD + quad * 8];
    short8 vc0 = *(const short8*)&Vtb[(size_t)m * S + quad * 8];
    short8 vc1 = *(const short8*)&Vtb[(size_t)(m + 16) * S + quad * 8];

    for (int i = 0; i < S / 32; i++) {
        floatx4 z = {};
        // swapped QK^T for all 4 q-tiles (lane(m,quad): P^T[k=quad*4+r][q=m])
        floatx4 t0[4], t1[4];
#pragma unroll
        for (int t = 0; t < 4; t++) {
            t0[t] = __builtin_amdgcn_mfma_f32_16x16x32_bf16(kf0, q[t], z, 0, 0, 0);
            t1[t] = __builtin_amdgcn_mfma_f32_16x16x32_bf16(kf1, q[t], z, 0, 0, 0);
        }
        // K prefetch for chunk i+1 (used at top of next iter, ~full iter ahead)
        int ktn = ((i + 1) * 32) & (S - 1);
        kf0 = *(const short8*)&Kb[(size_t)(ktn + m) * HD + quad * 8];
        kf1 = *(const short8*)&Kb[(size_t)(ktn + m + 16) * HD + quad * 8];

        // exp2 -> pack bf16 -> in-register transpose, per tile
        PW pw[4];
#pragma unroll
        for (int t = 0; t < 4; t++) {
            float e0 = __builtin_amdgcn_exp2f(t0[t][0]);
            float e1 = __builtin_amdgcn_exp2f(t0[t][1]);
            float e2 = __builtin_amdgcn_exp2f(t0[t][2]);
            float e3 = __builtin_amdgcn_exp2f(t0[t][3]);
            float e4 = __builtin_amdgcn_exp2f(t1[t][0]);
            float e5 = __builtin_amdgcn_exp2f(t1[t][1]);
            float e6 = __builtin_amdgcn_exp2f(t1[t][2]);
            float e7 = __builtin_amdgcn_exp2f(t1[t][3]);
            unsigned int w0, w1, w2, w3;
            asm("v_cvt_pk_bf16_f32 %0, %1, %2" : "=v"(w0) : "v"(e0), "v"(e1));
            asm("v_cvt_pk_bf16_f32 %0, %1, %2" : "=v"(w1) : "v"(e2), "v"(e3));
            asm("v_cvt_pk_bf16_f32 %0, %1, %2" : "=v"(w2) : "v"(e4), "v"(e5));
            asm("v_cvt_pk_bf16_f32 %0, %1, %2" : "=v"(w3) : "v"(e6), "v"(e7));
            asm("v_permlane32_swap_b32 %0, %1" : "+v"(w0), "+v"(w2));
            asm("v_permlane32_swap_b32 %0, %1" : "+v"(w1), "+v"(w3));
            asm("v_permlane16_swap_b32 %0, %1" : "+v"(w0), "+v"(w2));
            asm("v_permlane16_swap_b32 %0, %1" : "+v"(w1), "+v"(w3));
            pw[t].u[0] = w0; pw[t].u[1] = w1; pw[t].u[2] = w2; pw[t].u[3] = w3;
        }

        // PV + row-sum l (MFMA pipe), then V prefetch for chunk i+1
#pragma unroll
        for (int t = 0; t < 4; t++) {
            o0[t] = __builtin_amdgcn_mfma_f32_16x16x32_bf16(pw[t].s8, vc0, o0[t], 0, 0, 0);
            o1[t] = __builtin_amdgcn_mfma_f32_16x16x32_bf16(pw[t].s8, vc1, o1[t], 0, 0, 0);
            l[t]  = __builtin_amdgcn_mfma_f32_16x16x32_bf16(pw[t].s8, ones, l[t], 0, 0, 0);
        }
        vc0 = *(const short8*)&Vtb[(size_t)m * S + ktn + quad * 8];
        vc1 = *(const short8*)&Vtb[(size_t)(m + 16) * S + ktn + quad * 8];
    }

    // epilogue: l is row-aligned with O (row = quad*4+r), no shuffles
    int batch = bh >> 2, head = bh & 3;
    int col = head * HD + m;
#pragma unroll
    for (int t = 0; t < 4; t++) {
        int grow = batch * S + q0 + t * 16 + quad * 4;
#pragma unroll
        for (int r = 0; r < 4; r++) {
            float inv = 1.f / l[t][r];
            Ob[(size_t)(grow + r) * H + col]      = f32_to_bf16(o0[t][r] * inv);
            Ob[(size_t)(grow + r) * H + col + 16] = f32_to_bf16(o1[t][r] * inv);
        }
    }
}

// ---------- output projection GEMM (N=128) + bias, dual-dtype store ----------
__global__ __launch_bounds__(256) void mmout_kernel(const unsigned short* __restrict__ A,
        const unsigned short* __restrict__ B, const float* __restrict__ bias,
        void* __restrict__ out, const int* __restrict__ flags) {
    int tid = threadIdx.x, wave = tid >> 6, lane = tid & 63, m = lane & 15, quad = lane >> 4;
    int row0 = blockIdx.x * 64 + wave * 16;
    floatx4 acc[8] = {};
    for (int kc = 0; kc < H; kc += 32) {
        short8 af = *(const short8*)&A[(size_t)(row0 + m) * H + kc + quad * 8];
#pragma unroll
        for (int t = 0; t < 8; t++) {
            short8 bf = *(const short8*)&B[(size_t)(t * 16 + m) * H + kc + quad * 8];
            acc[t] = __builtin_amdgcn_mfma_f32_16x16x32_bf16(af, bf, acc[t], 0, 0, 0);
        }
    }
    int rbase = row0 + quad * 4;
    int f32o = flags[0];
#pragma unroll
    for (int t = 0; t < 8; t++) {
        int col = t * 16 + m;
        float bj = bias[col];
#pragma unroll
        for (int r = 0; r < 4; r++) {
            float v = acc[t][r] + bj;
            if (f32o) ((float*)out)[(size_t)(rbase + r) * H + col] = v;
            else ((unsigned short*)out)[(size_t)(rbase + r) * H + col] = f32_to_bf16(v);
        }
    }
}

extern "C" void kernel_launch(void* const* d_in, const int* in_sizes, int n_in,
                              void* d_out, int out_size, void* d_ws, size_t ws_size,
                              hipStream_t stream) {
    const void* x_raw    = d_in[0];
    const int*  ei_raw   = (const int*)d_in[1];
    const void* W1_raw   = d_in[2];
    const void* b1_raw   = d_in[3];
    const void* W2_raw   = d_in[4];
    const void* b2_raw   = d_in[5];
    const void* Wq_raw   = d_in[6];
    const void* bq_raw   = d_in[7];
    const void* Wo_raw   = d_in[8];
    const void* bo_raw   = d_in[9];

    char* ws = (char*)d_ws;
    size_t o = 0;
    auto alloc = [&](size_t bytes) { void* p = ws + o; o += (bytes + 1023) & ~1023ull; return p; };

    int*   flags     = (int*)  alloc(1024);
    int*   cnt       = (int*)  alloc((size_t)GN * 4);
    int*   row_start = (int*)  alloc((size_t)GN * 4);
    float* dinv      = (float*)alloc((size_t)GN * 4);
    int*   csr_src   = (int*)  alloc((size_t)ETOT * 4);
    unsigned short* xb   = (unsigned short*)alloc((size_t)GN * CIN * 2);
    unsigned short* zb   = (unsigned short*)alloc((size_t)GN * CIN * 2);
    unsigned short* W1T  = (unsigned short*)alloc((size_t)H * CIN * 2);
    unsigned short* W2T  = (unsigned short*)alloc((size_t)H * H * 2);
    unsigned short* Wqb  = (unsigned short*)alloc((size_t)QKV * H * 2);
    unsigned short* Wob  = (unsigned short*)alloc((size_t)H * H * 2);
    float* b1f = (float*)alloc(H * 4);
    float* b2f = (float*)alloc(H * 4);
    float* bqf = (float*)alloc(QKV * 4);
    float* bof = (float*)alloc(H * 4);
    unsigned short* y_bf = (unsigned short*)alloc((size_t)GN * H * 2);
    unsigned short* h_bf = (unsigned short*)alloc((size_t)GN * H * 2);
    unsigned short* Qx   = (unsigned short*)alloc((size_t)16 * S * HD * 2);
    unsigned short* Kx   = (unsigned short*)alloc((size_t)16 * S * HD * 2);
    unsigned short* Vtx  = (unsigned short*)alloc((size_t)16 * S * HD * 2);
    unsigned short* Obf  = y_bf;   // y dead after agg

    detect_kernel<<<1, 256, 0, stream>>>((const unsigned short*)x_raw, ei_raw, flags);

    // CSR build: count+scan+dinv+fill in one dispatch (LDS atomics)
    csr_kernel<<<G, NPG, 0, stream>>>(ei_raw, flags, cnt, row_start, dinv, csr_src);

    // conversion (x pre-scaled by dinv for the reassociated layer 1)
    conv_all_kernel<<<(CTOT + 255) / 256, 256, 0, stream>>>(
        x_raw, W1_raw, b1_raw, W2_raw, b2_raw, Wq_raw, bq_raw, Wo_raw, bo_raw,
        xb, W1T, W2T, Wqb, Wob, b1f, b2f, bqf, bof, dinv, flags);

    // GCN layer 1 aggregate (64ch), then fused GEMM1+GEMM2 (h stays in LDS)
    agg64_kernel<<<GN, CIN, 0, stream>>>(xb, row_start, cnt, csr_src, dinv, zb);
    gcn12_kernel<<<GN / 64, 256, 0, stream>>>(zb, W1T, b1f, W2T, dinv, y_bf);
    // GCN layer 2 aggregate + bias
    agg_kernel<<<GN, H, 0, stream>>>(y_bf, row_start, cnt, csr_src, dinv, b2f, h_bf);

    // attention
    mmqkv_kernel<<<GN / 64, 256, 0, stream>>>(h_bf, Wqb, bqf, Qx, Kx, Vtx);
    attn7_kernel<<<dim3(256), 256, 0, stream>>>(Qx, Kx, Vtx, Obf);
    mmout_kernel<<<GN / 64, 256, 0, stream>>>(Obf, Wob, bof, d_out, flags);
}